// Round 10
// baseline (188.387 us; speedup 1.0000x reference)
//
#include <hip/hip_runtime.h>
#include <stdint.h>

#define BATCH 16
#define NDET 25200
#define NCLS 80
#define PREDC 85
#define KTOP 2048
#define MAXDET 300
#define OUTC 86
#define CONF_THR 0.4f
#define IOU_THR 0.45f
#define MAXWH 4096.0f
#define MROWS (KTOP + 64)       // padded mask rows per batch
#define INVHI 0xBF800000u       // ~mono(-1.0f): score word of invalid rows
#define BMW (NCLS * 64)         // class bitmap words per batch (80 classes x 64)
#define NB 8192                 // flat histogram bins

#define REP32(F) F(0)F(1)F(2)F(3)F(4)F(5)F(6)F(7)F(8)F(9)F(10)F(11)F(12)F(13)F(14)F(15)F(16)F(17)F(18)F(19)F(20)F(21)F(22)F(23)F(24)F(25)F(26)F(27)F(28)F(29)F(30)F(31)

// ---- monotone float<->uint mapping (ascending) ----
__device__ __forceinline__ uint32_t mono_f32(float f) {
  uint32_t u = __float_as_uint(f);
  return (u & 0x80000000u) ? ~u : (u | 0x80000000u);
}
__device__ __forceinline__ float unmono_f32(uint32_t m) {
  uint32_t u = (m & 0x80000000u) ? (m & 0x7FFFFFFFu) : ~m;
  return __uint_as_float(u);
}

// K1: LDS-staged coalesced score/argmax. 256 threads: 4 chunks x 64 rows,
// 4 lanes per row (classes c = q+4k, strict > keeps lowest index per residue;
// cross-lane combine prefers higher val, then lower class — exact jnp.argmax).
// Writes score word (hi = ~mono(score)) and class byte; keys rebuilt on demand.
__global__ void __launch_bounds__(256) k_keys(const float* __restrict__ pred,
                                              uint32_t* __restrict__ sw,
                                              uint8_t* __restrict__ cls8) {
  __shared__ float lds[64 * PREDC];   // 21760 B
  int blk = blockIdx.x, tid = threadIdx.x;
  int q = tid & 3, r = tid >> 2;      // r in 0..63
  for (int ch = 0; ch < 4; ++ch) {
    __syncthreads();
    const float4* src4 = (const float4*)(pred + ((size_t)blk * 256 + (size_t)ch * 64) * PREDC);
    float4* l4 = (float4*)lds;
    for (int i = tid; i < (64 * PREDC) / 4; i += 256) l4[i] = src4[i];
    __syncthreads();
    const float* row = lds + r * PREDC;
    float obj = row[4];
    float best = -1e30f; int bc = 0;
    if (obj > CONF_THR) {
      for (int k = 0; k < 20; ++k) {
        int c = q + 4 * k;
        float s = __fmul_rn(row[5 + c], obj);   // single-rounded, no contraction
        if (s > best) { best = s; bc = c; }
      }
    }
    for (int d = 1; d <= 2; d <<= 1) {
      float vo = __shfl_xor(best, d);
      int co = __shfl_xor(bc, d);
      if (vo > best || (vo == best && co < bc)) { best = vo; bc = co; }
    }
    if (q == 0) {
      float score = -1.0f; uint32_t cl = 0;
      if (obj > CONF_THR && best > CONF_THR) { score = best; cl = (uint32_t)bc; }
      int rowIdx = blk * 256 + ch * 64 + r;
      sw[rowIdx] = ~mono_f32(score);
      cls8[rowIdx] = (uint8_t)cl;
    }
  }
}

// K2: fused radix-select + collect + bitonic sort + derive (+ class bitmap).
// Valid hi in [0x407FFFFF, 0x41333332] (score in (0.4,1]) => hi-0x40000000 < 2^25:
// TWO 13-bit passes find the exact score word; invalids (hi==INVHI) counted in
// registers into bin 8191. Exact tie refine on low=(n<<7)|cls (22 bits) if needed.
__global__ void __launch_bounds__(1024) k_sel(
    const uint32_t* __restrict__ sw, const uint8_t* __restrict__ cls8,
    const float* __restrict__ pred,
    uint32_t* __restrict__ s_n, float* __restrict__ s_score, float* __restrict__ s_clsf,
    uint32_t* __restrict__ s_cli, uint32_t* __restrict__ clsbm,
    float* __restrict__ s_box, float* __restrict__ s_obox, uint32_t* __restrict__ nvalid) {
  __shared__ uint64_t sk[KTOP];        // 16 KB
  __shared__ uint32_t hist[NB];        // 32 KB (reused as class bitmap later)
  __shared__ uint32_t seg[64];
  __shared__ uint32_t sh_digit, sh_cnt, sh_k;
  __shared__ uint32_t ncol, nv;
  int b = blockIdx.x, tid = threadIdx.x, lane = tid & 63;
  const uint32_t* swb = sw + (size_t)b * NDET;
  const uint8_t* clb = cls8 + (size_t)b * NDET;
  const uint4* sw4 = (const uint4*)swb;
  if (tid == 0) { sh_k = KTOP; ncol = 0; nv = 0; }

#define CLEAR_HIST() { __syncthreads(); \
  for (int i = tid; i < NB; i += 1024) hist[i] = 0; \
  __syncthreads(); }

#define FIND() { __syncthreads(); \
  if (tid < 64) { uint32_t s_ = 0; \
    for (int i_ = 0; i_ < NB / 64; ++i_) s_ += hist[tid * (NB / 64) + i_]; \
    seg[tid] = s_; } \
  __syncthreads(); \
  if (tid == 0) { uint32_t k_ = sh_k, cum_ = 0; int S_ = 0; \
    for (; S_ < 63; ++S_) { if (cum_ + seg[S_] >= k_) break; cum_ += seg[S_]; } \
    int d_ = S_ * (NB / 64); \
    for (;; ++d_) { if (cum_ + hist[d_] >= k_) break; cum_ += hist[d_]; } \
    sh_digit = (uint32_t)d_; sh_cnt = hist[d_]; sh_k = k_ - cum_; } \
  __syncthreads(); }

  // ---- pass A: bits [25:13] of (hi - 0x40000000); invalid -> bin 8191 ----
  CLEAR_HIST();
  {
    uint32_t invc = 0;
#define PA(s) { if ((s) == INVHI) ++invc; \
    else atomicAdd(&hist[((s) - 0x40000000u) >> 13], 1u); }
    for (int i = tid; i < NDET / 4; i += 1024) {
      uint4 v = sw4[i];
      PA(v.x) PA(v.y) PA(v.z) PA(v.w)
    }
    if (invc) atomicAdd(&hist[NB - 1], invc);
  }
  FIND();
  uint32_t dA = sh_digit;
  uint32_t sstar, E, r, Lstar = 0xFFFFFFFFu;
  if (dA == NB - 1) {
    sstar = INVHI; E = sh_cnt; r = sh_k;
  } else {
    // ---- pass B: bits [12:0] among prefix dA ----
    CLEAR_HIST();
    for (int i = tid; i < NDET / 4; i += 1024) {
      uint4 v = sw4[i];
#define PB(s) { if ((s) != INVHI && (((s) - 0x40000000u) >> 13) == dA) \
      atomicAdd(&hist[(s) & 0x1FFFu], 1u); }
      PB(v.x) PB(v.y) PB(v.z) PB(v.w)
    }
    FIND();
    sstar = 0x40000000u + (dA << 13) + sh_digit;
    E = sh_cnt; r = sh_k;
  }

  if (r < E) {
    // exact tie refine: r-th smallest low=(n<<7)|cls (22 bits) among hi==sstar.
    CLEAR_HIST();
    for (int n = tid; n < NDET; n += 1024) {
      if (swb[n] == sstar) {
        uint32_t low = ((uint32_t)n << 7) | clb[n];
        atomicAdd(&hist[low >> 11], 1u);
      }
    }
    FIND();
    uint32_t dr0 = sh_digit;
    CLEAR_HIST();
    for (int n = tid; n < NDET; n += 1024) {
      if (swb[n] == sstar) {
        uint32_t low = ((uint32_t)n << 7) | clb[n];
        if ((low >> 11) == dr0) atomicAdd(&hist[low & 0x7FFu], 1u);
      }
    }
    FIND();
    Lstar = (dr0 << 11) | sh_digit;
  }

  // ---- collect exactly KTOP keys ----
  for (int n = tid; n < NDET; n += 1024) {
    uint32_t hi = swb[n];
    uint32_t low = 0;
    bool inc = false;
    if (hi < sstar) inc = true;
    else if (hi == sstar) { low = ((uint32_t)n << 7) | clb[n]; inc = (low <= Lstar); }
    uint64_t ball = __ballot(inc);
    uint32_t bse = 0;
    if (lane == 0) bse = atomicAdd(&ncol, (uint32_t)__popcll(ball));
    bse = __shfl(bse, 0);
    if (inc) {
      if (hi < sstar) low = ((uint32_t)n << 7) | clb[n];
      uint32_t pos = bse + (uint32_t)__popcll(ball & ((1ull << lane) - 1ull));
      if (pos < KTOP) sk[pos] = ((uint64_t)hi << 32) | low;
    }
  }

  // ---- bitonic sort ascending (keys distinct: low contains n) ----
  for (int kk = 2; kk <= KTOP; kk <<= 1) {
    for (int j = kk >> 1; j > 0; j >>= 1) {
      __syncthreads();
      for (int i = tid; i < KTOP; i += 1024) {
        int ixj = i ^ j;
        if (ixj > i) {
          uint64_t a = sk[i], c = sk[ixj];
          bool asc = ((i & kk) == 0);
          if ((a > c) == asc) { sk[i] = c; sk[ixj] = a; }
        }
      }
    }
  }
  __syncthreads();

  // ---- class bitmap (reuse hist space; BMW=5120 <= NB) ----
  uint32_t* bm = hist;
  for (int i = tid; i < BMW; i += 1024) bm[i] = 0;
  __syncthreads();

  // ---- derive arrays ----
  for (int rr = tid; rr < KTOP; rr += 1024) {
    uint64_t key = sk[rr];
    float score = unmono_f32(~(uint32_t)(key >> 32));
    uint32_t low = (uint32_t)key;
    uint32_t n = low >> 7;
    uint32_t cls = low & 127u;
    uint64_t vball = __ballot(score > 0.0f);
    if (lane == 0) atomicAdd(&nv, (uint32_t)__popcll(vball));
    if (score > 0.0f) atomicOr(&bm[cls * 64 + (rr >> 5)], 1u << (rr & 31));
    const float* p = pred + ((size_t)b * NDET + n) * PREDC;
    float x = p[0], y = p[1], w = p[2], h = p[3];
    float hw = __fmul_rn(w, 0.5f), hh = __fmul_rn(h, 0.5f);
    float x1 = __fsub_rn(x, hw), y1 = __fsub_rn(y, hh);
    float x2 = __fadd_rn(x, hw), y2 = __fadd_rn(y, hh);
    float clsf = (float)cls;
    float off = __fmul_rn(clsf, MAXWH);
    size_t o = (size_t)b * KTOP + rr;
    s_n[o] = n;
    s_score[o] = score;
    s_clsf[o] = clsf;
    s_cli[o] = cls;
    s_box[o * 4 + 0] = x1; s_box[o * 4 + 1] = y1;
    s_box[o * 4 + 2] = x2; s_box[o * 4 + 3] = y2;
    s_obox[o * 4 + 0] = __fadd_rn(x1, off); s_obox[o * 4 + 1] = __fadd_rn(y1, off);
    s_obox[o * 4 + 2] = __fadd_rn(x2, off); s_obox[o * 4 + 3] = __fadd_rn(y2, off);
  }
  __syncthreads();
  for (int i = tid; i < BMW; i += 1024) clsbm[(size_t)b * BMW + i] = bm[i];
  if (tid == 0) nvalid[b] = nv;
}

// K5: suppression bitmask via per-class rank bitmap (cross-class IoU == 0 exactly).
__global__ void k_mask(const float* __restrict__ s_obox, const uint32_t* __restrict__ s_cli,
                       const uint32_t* __restrict__ clsbm, const uint32_t* __restrict__ nvalid,
                       uint32_t* __restrict__ mask, uint32_t* __restrict__ diag) {
  int gid = blockIdx.x * blockDim.x + threadIdx.x; // BATCH*KTOP*64 threads
  int w = gid & 63;
  int i = (gid >> 6) & (KTOP - 1);
  int b = gid >> 17;
  if (i >= (int)nvalid[b]) return;
  int iw = i >> 5, ib = i & 31;
  uint32_t word = 0;
  if (w >= iw) {
    uint32_t ci = s_cli[(size_t)b * KTOP + i];
    uint32_t bmw = clsbm[(size_t)b * BMW + ci * 64 + w];
    uint32_t uptri = (w > iw) ? 0xFFFFFFFFu : ((ib == 31) ? 0u : (0xFFFFFFFFu << (ib + 1)));
    uint32_t mbits = bmw & uptri;
    if (mbits) {
      const float* bi = s_obox + ((size_t)b * KTOP + i) * 4;
      float ix1 = bi[0], iy1 = bi[1], ix2 = bi[2], iy2 = bi[3];
      float iarea = __fmul_rn(__fsub_rn(ix2, ix1), __fsub_rn(iy2, iy1));
      int j0 = w * 32;
      do {
        int t = __ffs(mbits) - 1;
        mbits &= mbits - 1;
        int j = j0 + t;
        const float* bj = s_obox + ((size_t)b * KTOP + j) * 4;
        float jx1 = bj[0], jy1 = bj[1], jx2 = bj[2], jy2 = bj[3];
        float jarea = __fmul_rn(__fsub_rn(jx2, jx1), __fsub_rn(jy2, jy1));
        float ltx = fmaxf(ix1, jx1), lty = fmaxf(iy1, jy1);
        float rbx = fminf(ix2, jx2), rby = fminf(iy2, jy2);
        float wx = fmaxf(__fsub_rn(rbx, ltx), 0.0f);
        float wy = fmaxf(__fsub_rn(rby, lty), 0.0f);
        float inter = __fmul_rn(wx, wy);
        float denom = __fadd_rn(__fsub_rn(__fadd_rn(iarea, jarea), inter), 1e-7f);
        float iou = __fdiv_rn(inter, denom);
        if (iou > IOU_THR) word |= (1u << t);
      } while (mbits);
    }
  }
  mask[((size_t)b * MROWS + i) * 64 + w] = word;
  if (w == iw) diag[(size_t)b * KTOP + i] = word;
}

// K6: sequential greedy pass, one wave per batch; lane l owns removed word l.
__global__ void __launch_bounds__(64, 1) k_nms(
    const uint32_t* __restrict__ mask, const uint32_t* __restrict__ diag,
    const uint32_t* __restrict__ nvalid, uint32_t* __restrict__ supp) {
  __shared__ uint32_t ldsd[KTOP];
  int b = blockIdx.x;
  int lane = threadIdx.x; // 64 threads = 1 wave
  int nv = (int)nvalid[b];
  const uint32_t* mbl = mask + (size_t)b * MROWS * 64 + lane;
  const uint32_t* db = diag + (size_t)b * KTOP;
  for (int i = lane; i < KTOP; i += 64) ldsd[i] = db[i];
  __syncthreads();
  uint32_t removed = 0;
  int ngrp = (nv + 31) >> 5;
  for (int g = 0; g < ngrp; ++g) {
    int base = g * 32;
    int rem = nv - base;
    uint32_t vm = (rem >= 32) ? 0xFFFFFFFFu : ((1u << rem) - 1u);
    const uint32_t* rp = mbl + (size_t)base * 64;
#define DECL_R(d) uint32_t R##d = rp[(size_t)(d) * 64];
    REP32(DECL_R)
#define PIN_R(d) asm volatile("" : "+v"(R##d));
    REP32(PIN_R)
#define DECL_S(d) uint32_t S##d = ldsd[base + d] & ((uint32_t)0 - ((vm >> d) & 1u));
    REP32(DECL_S)
    uint32_t curw = __shfl(removed, g);
    uint32_t cinit = curw;
#define CHAIN(d) { uint32_t m_ = ((curw >> d) & 1u) - 1u; curw |= m_ & S##d; }
    REP32(CHAIN)
    uint32_t am = vm & ~(curw | cinit);
#define APPLY(d) removed |= R##d & ((uint32_t)0 - ((am >> d) & 1u));
    REP32(APPLY)
  }
  supp[b * 64 + lane] = removed;
}

// K7: write the ENTIRE output into a DEVICE staging buffer (fast HBM writes).
__global__ void __launch_bounds__(1024) k_out(
    const uint32_t* __restrict__ supp, const uint32_t* __restrict__ nvalid,
    const uint32_t* __restrict__ s_n, const float* __restrict__ s_score,
    const float* __restrict__ s_clsf, const float* __restrict__ s_box,
    const float* __restrict__ logits, float* __restrict__ outst) {
  __shared__ uint32_t keepw[64];
  __shared__ uint32_t pfx[64];
  __shared__ int src[MAXDET];
  int b = blockIdx.x, tid = threadIdx.x;
  int nv = (int)nvalid[b];
  if (tid < 64) {
    uint32_t sw2 = supp[b * 64 + tid];
    int lo = tid * 32;
    uint32_t vm;
    if (nv >= lo + 32) vm = 0xFFFFFFFFu;
    else if (nv <= lo) vm = 0u;
    else vm = (1u << (nv - lo)) - 1u;
    keepw[tid] = (~sw2) & vm;
  }
  for (int s = tid; s < MAXDET; s += 1024) src[s] = -1;
  __syncthreads();
  if (tid == 0) {
    uint32_t c = 0;
    for (int w = 0; w < 64; ++w) { pfx[w] = c; c += __popc(keepw[w]); }
  }
  __syncthreads();
  for (int r = tid; r < KTOP; r += 1024) {
    int w = r >> 5, t = r & 31;
    uint32_t kw = keepw[w];
    if (!((kw >> t) & 1u)) continue;
    uint32_t rank = pfx[w] + (uint32_t)__popc(kw & ((1u << t) - 1u));
    if (rank < MAXDET) src[rank] = r;
  }
  __syncthreads();
  const float* lg = logits + (size_t)b * NDET * NCLS;
  float* ob = outst + (size_t)b * MAXDET * OUTC;
  for (int e = tid; e < MAXDET * OUTC; e += 1024) {
    int slot = e / OUTC;
    int c = e - slot * OUTC;
    int r = src[slot];
    float v = 0.0f;
    if (r >= 0) {
      size_t o = (size_t)b * KTOP + r;
      if (c < 4) v = s_box[o * 4 + c];
      else if (c == 4) v = s_score[o];
      else if (c == 5) v = s_clsf[o];
      else v = lg[(size_t)s_n[o] * NCLS + (c - 6)];
    }
    ob[e] = v;
  }
}

// K8: wide parallel copy staging -> d_out (PCIe-resident). 16B stores x 103K
// threads maximize outstanding PCIe writes; also makes the out-path cost
// visible in rocprof (replaces opaque memcpy node).
__global__ void k_copy(const float4* __restrict__ src, float4* __restrict__ dst, int n4) {
  int i = blockIdx.x * blockDim.x + threadIdx.x;
  if (i < n4) dst[i] = src[i];
}

extern "C" void kernel_launch(void* const* d_in, const int* in_sizes, int n_in,
                              void* d_out, int out_size, void* d_ws, size_t ws_size,
                              hipStream_t stream) {
  const float* pred = (const float*)d_in[0];
  const float* logits = (const float*)d_in[1];

  char* ws = (char*)d_ws;
  size_t off = 0;
  auto alloc = [&](size_t bytes) -> void* {
    void* p = ws + off;
    off += (bytes + 255) & ~(size_t)255;
    return p;
  };
  uint32_t* sw    = (uint32_t*)alloc((size_t)BATCH * NDET * 4);
  uint8_t*  cls8  = (uint8_t*)alloc((size_t)BATCH * NDET);
  uint32_t* s_n   = (uint32_t*)alloc((size_t)BATCH * KTOP * 4);
  float*    s_sc  = (float*)alloc((size_t)BATCH * KTOP * 4);
  float*    s_cl  = (float*)alloc((size_t)BATCH * KTOP * 4);
  uint32_t* s_cli = (uint32_t*)alloc((size_t)BATCH * KTOP * 4);
  uint32_t* clsbm = (uint32_t*)alloc((size_t)BATCH * BMW * 4);
  float*    s_box = (float*)alloc((size_t)BATCH * KTOP * 16);
  float*    s_ob  = (float*)alloc((size_t)BATCH * KTOP * 16);
  uint32_t* nval  = (uint32_t*)alloc((size_t)BATCH * 4);
  uint32_t* mask  = (uint32_t*)alloc((size_t)BATCH * MROWS * 64 * 4);
  uint32_t* diag  = (uint32_t*)alloc((size_t)BATCH * KTOP * 4);
  uint32_t* suppw = (uint32_t*)alloc((size_t)BATCH * 64 * 4);
  float*    outst = (float*)alloc((size_t)BATCH * MAXDET * OUTC * 4);
  (void)ws_size; (void)in_sizes; (void)n_in;

  k_keys<<<(BATCH * NDET) / 256, 256, 0, stream>>>(pred, sw, cls8);
  k_sel<<<BATCH, 1024, 0, stream>>>(sw, cls8, pred, s_n, s_sc, s_cl, s_cli, clsbm, s_box, s_ob, nval);
  k_mask<<<(BATCH * KTOP * 64) / 256, 256, 0, stream>>>(s_ob, s_cli, clsbm, nval, mask, diag);
  k_nms<<<BATCH, 64, 0, stream>>>(mask, diag, nval, suppw);
  k_out<<<BATCH, 1024, 0, stream>>>(suppw, nval, s_n, s_sc, s_cl, s_box, logits, outst);
  int n4 = out_size / 4;
  k_copy<<<(n4 + 255) / 256, 256, 0, stream>>>((const float4*)outst, (float4*)d_out, n4);
}

// Round 12
// 173.834 us; speedup vs baseline: 1.0837x; 1.0837x over previous
//
#include <hip/hip_runtime.h>
#include <stdint.h>

#define BATCH 16
#define NDET 25200
#define NCLS 80
#define PREDC 85
#define KTOP 2048
#define MAXDET 300
#define OUTC 86
#define CONF_THR 0.4f
#define IOU_THR 0.45f
#define MAXWH 4096.0f
#define MROWS (KTOP + 64)       // padded mask rows per batch
#define INVHI 0xBF800000u       // ~mono(-1.0f): score word of invalid rows
#define BMW (NCLS * 64)         // class bitmap words per batch (80 classes x 64)
#define NB 8192                 // flat histogram bins

typedef float fx4 __attribute__((ext_vector_type(4)));

#define REP32(F) F(0)F(1)F(2)F(3)F(4)F(5)F(6)F(7)F(8)F(9)F(10)F(11)F(12)F(13)F(14)F(15)F(16)F(17)F(18)F(19)F(20)F(21)F(22)F(23)F(24)F(25)F(26)F(27)F(28)F(29)F(30)F(31)

// ---- monotone float<->uint mapping (ascending) ----
__device__ __forceinline__ uint32_t mono_f32(float f) {
  uint32_t u = __float_as_uint(f);
  return (u & 0x80000000u) ? ~u : (u | 0x80000000u);
}
__device__ __forceinline__ float unmono_f32(uint32_t m) {
  uint32_t u = (m & 0x80000000u) ? (m & 0x7FFFFFFFu) : ~m;
  return __uint_as_float(u);
}

// K1: LDS-staged coalesced score/argmax (4 lanes/row, exact first-max tie-break).
__global__ void __launch_bounds__(256) k_keys(const float* __restrict__ pred,
                                              uint32_t* __restrict__ sw,
                                              uint8_t* __restrict__ cls8) {
  __shared__ float lds[64 * PREDC];   // 21760 B
  int blk = blockIdx.x, tid = threadIdx.x;
  int q = tid & 3, r = tid >> 2;      // r in 0..63
  for (int ch = 0; ch < 4; ++ch) {
    __syncthreads();
    const float4* src4 = (const float4*)(pred + ((size_t)blk * 256 + (size_t)ch * 64) * PREDC);
    float4* l4 = (float4*)lds;
    for (int i = tid; i < (64 * PREDC) / 4; i += 256) l4[i] = src4[i];
    __syncthreads();
    const float* row = lds + r * PREDC;
    float obj = row[4];
    float best = -1e30f; int bc = 0;
    if (obj > CONF_THR) {
      for (int k = 0; k < 20; ++k) {
        int c = q + 4 * k;
        float s = __fmul_rn(row[5 + c], obj);   // single-rounded, no contraction
        if (s > best) { best = s; bc = c; }
      }
    }
    for (int d = 1; d <= 2; d <<= 1) {
      float vo = __shfl_xor(best, d);
      int co = __shfl_xor(bc, d);
      if (vo > best || (vo == best && co < bc)) { best = vo; bc = co; }
    }
    if (q == 0) {
      float score = -1.0f; uint32_t cl = 0;
      if (obj > CONF_THR && best > CONF_THR) { score = best; cl = (uint32_t)bc; }
      int rowIdx = blk * 256 + ch * 64 + r;
      sw[rowIdx] = ~mono_f32(score);
      cls8[rowIdx] = (uint8_t)cl;
    }
  }
}

// K2: fused radix-select (2x13-bit) + exact tie refine + collect + bitonic sort
// + derive (+ class bitmap). One 1024-thread block per batch.
__global__ void __launch_bounds__(1024) k_sel(
    const uint32_t* __restrict__ sw, const uint8_t* __restrict__ cls8,
    const float* __restrict__ pred,
    uint32_t* __restrict__ s_n, float* __restrict__ s_score, float* __restrict__ s_clsf,
    uint32_t* __restrict__ s_cli, uint32_t* __restrict__ clsbm,
    float* __restrict__ s_box, float* __restrict__ s_obox, uint32_t* __restrict__ nvalid) {
  __shared__ uint64_t sk[KTOP];        // 16 KB
  __shared__ uint32_t hist[NB];        // 32 KB (reused as class bitmap later)
  __shared__ uint32_t seg[64];
  __shared__ uint32_t sh_digit, sh_cnt, sh_k;
  __shared__ uint32_t ncol, nv;
  int b = blockIdx.x, tid = threadIdx.x, lane = tid & 63;
  const uint32_t* swb = sw + (size_t)b * NDET;
  const uint8_t* clb = cls8 + (size_t)b * NDET;
  const uint4* sw4 = (const uint4*)swb;
  if (tid == 0) { sh_k = KTOP; ncol = 0; nv = 0; }

#define CLEAR_HIST() { __syncthreads(); \
  for (int i = tid; i < NB; i += 1024) hist[i] = 0; \
  __syncthreads(); }

#define FIND() { __syncthreads(); \
  if (tid < 64) { uint32_t s_ = 0; \
    for (int i_ = 0; i_ < NB / 64; ++i_) s_ += hist[tid * (NB / 64) + i_]; \
    seg[tid] = s_; } \
  __syncthreads(); \
  if (tid == 0) { uint32_t k_ = sh_k, cum_ = 0; int S_ = 0; \
    for (; S_ < 63; ++S_) { if (cum_ + seg[S_] >= k_) break; cum_ += seg[S_]; } \
    int d_ = S_ * (NB / 64); \
    for (;; ++d_) { if (cum_ + hist[d_] >= k_) break; cum_ += hist[d_]; } \
    sh_digit = (uint32_t)d_; sh_cnt = hist[d_]; sh_k = k_ - cum_; } \
  __syncthreads(); }

  // ---- pass A: bits [25:13] of (hi - 0x40000000); invalid -> bin 8191 ----
  CLEAR_HIST();
  {
    uint32_t invc = 0;
#define PA(s) { if ((s) == INVHI) ++invc; \
    else atomicAdd(&hist[((s) - 0x40000000u) >> 13], 1u); }
    for (int i = tid; i < NDET / 4; i += 1024) {
      uint4 v = sw4[i];
      PA(v.x) PA(v.y) PA(v.z) PA(v.w)
    }
    if (invc) atomicAdd(&hist[NB - 1], invc);
  }
  FIND();
  uint32_t dA = sh_digit;
  uint32_t sstar, E, r, Lstar = 0xFFFFFFFFu;
  if (dA == NB - 1) {
    sstar = INVHI; E = sh_cnt; r = sh_k;
  } else {
    // ---- pass B: bits [12:0] among prefix dA ----
    CLEAR_HIST();
    for (int i = tid; i < NDET / 4; i += 1024) {
      uint4 v = sw4[i];
#define PB(s) { if ((s) != INVHI && (((s) - 0x40000000u) >> 13) == dA) \
      atomicAdd(&hist[(s) & 0x1FFFu], 1u); }
      PB(v.x) PB(v.y) PB(v.z) PB(v.w)
    }
    FIND();
    sstar = 0x40000000u + (dA << 13) + sh_digit;
    E = sh_cnt; r = sh_k;
  }

  if (r < E) {
    // exact tie refine: r-th smallest low=(n<<7)|cls (22 bits) among hi==sstar.
    CLEAR_HIST();
    for (int n = tid; n < NDET; n += 1024) {
      if (swb[n] == sstar) {
        uint32_t low = ((uint32_t)n << 7) | clb[n];
        atomicAdd(&hist[low >> 11], 1u);
      }
    }
    FIND();
    uint32_t dr0 = sh_digit;
    CLEAR_HIST();
    for (int n = tid; n < NDET; n += 1024) {
      if (swb[n] == sstar) {
        uint32_t low = ((uint32_t)n << 7) | clb[n];
        if ((low >> 11) == dr0) atomicAdd(&hist[low & 0x7FFu], 1u);
      }
    }
    FIND();
    Lstar = (dr0 << 11) | sh_digit;
  }

  // ---- collect exactly KTOP keys ----
  for (int n = tid; n < NDET; n += 1024) {
    uint32_t hi = swb[n];
    uint32_t low = 0;
    bool inc = false;
    if (hi < sstar) inc = true;
    else if (hi == sstar) { low = ((uint32_t)n << 7) | clb[n]; inc = (low <= Lstar); }
    uint64_t ball = __ballot(inc);
    uint32_t bse = 0;
    if (lane == 0) bse = atomicAdd(&ncol, (uint32_t)__popcll(ball));
    bse = __shfl(bse, 0);
    if (inc) {
      if (hi < sstar) low = ((uint32_t)n << 7) | clb[n];
      uint32_t pos = bse + (uint32_t)__popcll(ball & ((1ull << lane) - 1ull));
      if (pos < KTOP) sk[pos] = ((uint64_t)hi << 32) | low;
    }
  }

  // ---- bitonic sort ascending (keys distinct: low contains n) ----
  for (int kk = 2; kk <= KTOP; kk <<= 1) {
    for (int j = kk >> 1; j > 0; j >>= 1) {
      __syncthreads();
      for (int i = tid; i < KTOP; i += 1024) {
        int ixj = i ^ j;
        if (ixj > i) {
          uint64_t a = sk[i], c = sk[ixj];
          bool asc = ((i & kk) == 0);
          if ((a > c) == asc) { sk[i] = c; sk[ixj] = a; }
        }
      }
    }
  }
  __syncthreads();

  // ---- class bitmap (reuse hist space; BMW=5120 <= NB) ----
  uint32_t* bm = hist;
  for (int i = tid; i < BMW; i += 1024) bm[i] = 0;
  __syncthreads();

  // ---- derive arrays ----
  for (int rr = tid; rr < KTOP; rr += 1024) {
    uint64_t key = sk[rr];
    float score = unmono_f32(~(uint32_t)(key >> 32));
    uint32_t low = (uint32_t)key;
    uint32_t n = low >> 7;
    uint32_t cls = low & 127u;
    uint64_t vball = __ballot(score > 0.0f);
    if (lane == 0) atomicAdd(&nv, (uint32_t)__popcll(vball));
    if (score > 0.0f) atomicOr(&bm[cls * 64 + (rr >> 5)], 1u << (rr & 31));
    const float* p = pred + ((size_t)b * NDET + n) * PREDC;
    float x = p[0], y = p[1], w = p[2], h = p[3];
    float hw = __fmul_rn(w, 0.5f), hh = __fmul_rn(h, 0.5f);
    float x1 = __fsub_rn(x, hw), y1 = __fsub_rn(y, hh);
    float x2 = __fadd_rn(x, hw), y2 = __fadd_rn(y, hh);
    float clsf = (float)cls;
    float off = __fmul_rn(clsf, MAXWH);
    size_t o = (size_t)b * KTOP + rr;
    s_n[o] = n;
    s_score[o] = score;
    s_clsf[o] = clsf;
    s_cli[o] = cls;
    s_box[o * 4 + 0] = x1; s_box[o * 4 + 1] = y1;
    s_box[o * 4 + 2] = x2; s_box[o * 4 + 3] = y2;
    s_obox[o * 4 + 0] = __fadd_rn(x1, off); s_obox[o * 4 + 1] = __fadd_rn(y1, off);
    s_obox[o * 4 + 2] = __fadd_rn(x2, off); s_obox[o * 4 + 3] = __fadd_rn(y2, off);
  }
  __syncthreads();
  for (int i = tid; i < BMW; i += 1024) clsbm[(size_t)b * BMW + i] = bm[i];
  if (tid == 0) nvalid[b] = nv;
}

// K5: suppression bitmask via per-class rank bitmap (cross-class IoU == 0 exactly).
__global__ void k_mask(const float* __restrict__ s_obox, const uint32_t* __restrict__ s_cli,
                       const uint32_t* __restrict__ clsbm, const uint32_t* __restrict__ nvalid,
                       uint32_t* __restrict__ mask, uint32_t* __restrict__ diag) {
  int gid = blockIdx.x * blockDim.x + threadIdx.x; // BATCH*KTOP*64 threads
  int w = gid & 63;
  int i = (gid >> 6) & (KTOP - 1);
  int b = gid >> 17;
  if (i >= (int)nvalid[b]) return;
  int iw = i >> 5, ib = i & 31;
  uint32_t word = 0;
  if (w >= iw) {
    uint32_t ci = s_cli[(size_t)b * KTOP + i];
    uint32_t bmw = clsbm[(size_t)b * BMW + ci * 64 + w];
    uint32_t uptri = (w > iw) ? 0xFFFFFFFFu : ((ib == 31) ? 0u : (0xFFFFFFFFu << (ib + 1)));
    uint32_t mbits = bmw & uptri;
    if (mbits) {
      const float* bi = s_obox + ((size_t)b * KTOP + i) * 4;
      float ix1 = bi[0], iy1 = bi[1], ix2 = bi[2], iy2 = bi[3];
      float iarea = __fmul_rn(__fsub_rn(ix2, ix1), __fsub_rn(iy2, iy1));
      int j0 = w * 32;
      do {
        int t = __ffs(mbits) - 1;
        mbits &= mbits - 1;
        int j = j0 + t;
        const float* bj = s_obox + ((size_t)b * KTOP + j) * 4;
        float jx1 = bj[0], jy1 = bj[1], jx2 = bj[2], jy2 = bj[3];
        float jarea = __fmul_rn(__fsub_rn(jx2, jx1), __fsub_rn(jy2, jy1));
        float ltx = fmaxf(ix1, jx1), lty = fmaxf(iy1, jy1);
        float rbx = fminf(ix2, jx2), rby = fminf(iy2, jy2);
        float wx = fmaxf(__fsub_rn(rbx, ltx), 0.0f);
        float wy = fmaxf(__fsub_rn(rby, lty), 0.0f);
        float inter = __fmul_rn(wx, wy);
        float denom = __fadd_rn(__fsub_rn(__fadd_rn(iarea, jarea), inter), 1e-7f);
        float iou = __fdiv_rn(inter, denom);
        if (iou > IOU_THR) word |= (1u << t);
      } while (mbits);
    }
  }
  mask[((size_t)b * MROWS + i) * 64 + w] = word;
  if (w == iw) diag[(size_t)b * KTOP + i] = word;
}

// K6: sequential greedy pass + src-table build (fused rank computation).
__global__ void __launch_bounds__(64, 1) k_nms(
    const uint32_t* __restrict__ mask, const uint32_t* __restrict__ diag,
    const uint32_t* __restrict__ nvalid, int* __restrict__ srcTab) {
  __shared__ uint32_t ldsd[KTOP];
  int b = blockIdx.x;
  int lane = threadIdx.x; // 64 threads = 1 wave
  int nv = (int)nvalid[b];
  const uint32_t* mbl = mask + (size_t)b * MROWS * 64 + lane;
  const uint32_t* db = diag + (size_t)b * KTOP;
  for (int i = lane; i < KTOP; i += 64) ldsd[i] = db[i];
  __syncthreads();
  uint32_t removed = 0;
  int ngrp = (nv + 31) >> 5;
  for (int g = 0; g < ngrp; ++g) {
    int base = g * 32;
    int rem = nv - base;
    uint32_t vm = (rem >= 32) ? 0xFFFFFFFFu : ((1u << rem) - 1u);
    const uint32_t* rp = mbl + (size_t)base * 64;
#define DECL_R(d) uint32_t R##d = rp[(size_t)(d) * 64];
    REP32(DECL_R)
#define PIN_R(d) asm volatile("" : "+v"(R##d));
    REP32(PIN_R)
#define DECL_S(d) uint32_t S##d = ldsd[base + d] & ((uint32_t)0 - ((vm >> d) & 1u));
    REP32(DECL_S)
    uint32_t curw = __shfl(removed, g);
    uint32_t cinit = curw;
#define CHAIN(d) { uint32_t m_ = ((curw >> d) & 1u) - 1u; curw |= m_ & S##d; }
    REP32(CHAIN)
    uint32_t am = vm & ~(curw | cinit);
#define APPLY(d) removed |= R##d & ((uint32_t)0 - ((am >> d) & 1u));
    REP32(APPLY)
  }
  // ---- build src table: slot -> kept rank r (or -1) ----
  int lo = lane * 32;
  uint32_t vmw;
  if (nv >= lo + 32) vmw = 0xFFFFFFFFu;
  else if (nv <= lo) vmw = 0u;
  else vmw = (1u << (nv - lo)) - 1u;
  uint32_t keep = (~removed) & vmw;
  int* sb = srcTab + b * MAXDET;
  for (int s = lane; s < MAXDET; s += 64) sb[s] = -1;
  __syncthreads();   // drain init stores before scatter
  uint32_t cnt = __popc(keep);
  uint32_t scan = cnt;
  for (int d = 1; d < 64; d <<= 1) {
    uint32_t v = __shfl_up(scan, d);
    if (lane >= d) scan += v;
  }
  uint32_t pfx = scan - cnt;   // exclusive prefix
  while (keep) {
    int t = __ffs(keep) - 1;
    keep &= keep - 1;
    if (pfx < MAXDET) sb[pfx] = lo + t;
    ++pfx;
  }
}

// K7: gather + DIRECT write to d_out (PCIe), 16B nontemporal stores, max TLP.
__global__ void __launch_bounds__(256) k_outw(
    const int* __restrict__ srcTab, const uint32_t* __restrict__ s_n,
    const float* __restrict__ s_score, const float* __restrict__ s_clsf,
    const float* __restrict__ s_box, const float* __restrict__ logits,
    fx4* __restrict__ dout) {
  int i = blockIdx.x * 256 + threadIdx.x;
  if (i >= (BATCH * MAXDET * OUTC) / 4) return;
  float v0, v1, v2, v3;
#define GETV(k, dst) { \
    int idx = i * 4 + k; \
    int b = idx / (MAXDET * OUTC); \
    int rem = idx - b * (MAXDET * OUTC); \
    int slot = rem / OUTC; \
    int c = rem - slot * OUTC; \
    int r = srcTab[b * MAXDET + slot]; \
    float x = 0.0f; \
    if (r >= 0) { \
      size_t o = (size_t)b * KTOP + r; \
      if (c < 4) x = s_box[o * 4 + c]; \
      else if (c == 4) x = s_score[o]; \
      else if (c == 5) x = s_clsf[o]; \
      else x = logits[((size_t)b * NDET + s_n[o]) * NCLS + (c - 6)]; \
    } \
    dst = x; }
  GETV(0, v0) GETV(1, v1) GETV(2, v2) GETV(3, v3)
  fx4 f4 = {v0, v1, v2, v3};
  __builtin_nontemporal_store(f4, &dout[i]);
}

extern "C" void kernel_launch(void* const* d_in, const int* in_sizes, int n_in,
                              void* d_out, int out_size, void* d_ws, size_t ws_size,
                              hipStream_t stream) {
  const float* pred = (const float*)d_in[0];
  const float* logits = (const float*)d_in[1];

  char* ws = (char*)d_ws;
  size_t off = 0;
  auto alloc = [&](size_t bytes) -> void* {
    void* p = ws + off;
    off += (bytes + 255) & ~(size_t)255;
    return p;
  };
  uint32_t* sw    = (uint32_t*)alloc((size_t)BATCH * NDET * 4);
  uint8_t*  cls8  = (uint8_t*)alloc((size_t)BATCH * NDET);
  uint32_t* s_n   = (uint32_t*)alloc((size_t)BATCH * KTOP * 4);
  float*    s_sc  = (float*)alloc((size_t)BATCH * KTOP * 4);
  float*    s_cl  = (float*)alloc((size_t)BATCH * KTOP * 4);
  uint32_t* s_cli = (uint32_t*)alloc((size_t)BATCH * KTOP * 4);
  uint32_t* clsbm = (uint32_t*)alloc((size_t)BATCH * BMW * 4);
  float*    s_box = (float*)alloc((size_t)BATCH * KTOP * 16);
  float*    s_ob  = (float*)alloc((size_t)BATCH * KTOP * 16);
  uint32_t* nval  = (uint32_t*)alloc((size_t)BATCH * 4);
  uint32_t* mask  = (uint32_t*)alloc((size_t)BATCH * MROWS * 64 * 4);
  uint32_t* diag  = (uint32_t*)alloc((size_t)BATCH * KTOP * 4);
  int*      srcT  = (int*)alloc((size_t)BATCH * MAXDET * 4);
  (void)ws_size; (void)in_sizes; (void)n_in;

  k_keys<<<(BATCH * NDET) / 256, 256, 0, stream>>>(pred, sw, cls8);
  k_sel<<<BATCH, 1024, 0, stream>>>(sw, cls8, pred, s_n, s_sc, s_cl, s_cli, clsbm, s_box, s_ob, nval);
  k_mask<<<(BATCH * KTOP * 64) / 256, 256, 0, stream>>>(s_ob, s_cli, clsbm, nval, mask, diag);
  k_nms<<<BATCH, 64, 0, stream>>>(mask, diag, nval, srcT);
  int n4 = (BATCH * MAXDET * OUTC) / 4;
  k_outw<<<(n4 + 255) / 256, 256, 0, stream>>>(srcT, s_n, s_sc, s_cl, s_box, logits, (fx4*)d_out);
}

// Round 13
// 117.835 us; speedup vs baseline: 1.5987x; 1.4752x over previous
//
#include <hip/hip_runtime.h>
#include <stdint.h>

#define BATCH 16
#define NDET 25200
#define NCLS 80
#define PREDC 85
#define KTOP 2048
#define MAXDET 300
#define OUTC 86
#define CONF_THR 0.4f
#define IOU_THR 0.45f
#define MAXWH 4096.0f
#define INVHI 0xBF800000u       // ~mono(-1.0f): score word of invalid rows
#define BMW (NCLS * 64)         // class bitmap words per batch (80 classes x 64)
#define NB 8192                 // flat histogram bins

typedef float fx4 __attribute__((ext_vector_type(4)));

// ---- monotone float<->uint mapping (ascending) ----
__device__ __forceinline__ uint32_t mono_f32(float f) {
  uint32_t u = __float_as_uint(f);
  return (u & 0x80000000u) ? ~u : (u | 0x80000000u);
}
__device__ __forceinline__ float unmono_f32(uint32_t m) {
  uint32_t u = (m & 0x80000000u) ? (m & 0x7FFFFFFFu) : ~m;
  return __uint_as_float(u);
}

// K1: LDS-staged coalesced score/argmax (4 lanes/row, exact first-max tie-break).
__global__ void __launch_bounds__(256) k_keys(const float* __restrict__ pred,
                                              uint32_t* __restrict__ sw,
                                              uint8_t* __restrict__ cls8) {
  __shared__ float lds[64 * PREDC];   // 21760 B
  int blk = blockIdx.x, tid = threadIdx.x;
  int q = tid & 3, r = tid >> 2;      // r in 0..63
  for (int ch = 0; ch < 4; ++ch) {
    __syncthreads();
    const float4* src4 = (const float4*)(pred + ((size_t)blk * 256 + (size_t)ch * 64) * PREDC);
    float4* l4 = (float4*)lds;
    for (int i = tid; i < (64 * PREDC) / 4; i += 256) l4[i] = src4[i];
    __syncthreads();
    const float* row = lds + r * PREDC;
    float obj = row[4];
    float best = -1e30f; int bc = 0;
    if (obj > CONF_THR) {
      for (int k = 0; k < 20; ++k) {
        int c = q + 4 * k;
        float s = __fmul_rn(row[5 + c], obj);   // single-rounded, no contraction
        if (s > best) { best = s; bc = c; }
      }
    }
    for (int d = 1; d <= 2; d <<= 1) {
      float vo = __shfl_xor(best, d);
      int co = __shfl_xor(bc, d);
      if (vo > best || (vo == best && co < bc)) { best = vo; bc = co; }
    }
    if (q == 0) {
      float score = -1.0f; uint32_t cl = 0;
      if (obj > CONF_THR && best > CONF_THR) { score = best; cl = (uint32_t)bc; }
      int rowIdx = blk * 256 + ch * 64 + r;
      sw[rowIdx] = ~mono_f32(score);
      cls8[rowIdx] = (uint8_t)cl;
    }
  }
}

// K2: fused radix-select (2x13-bit) + exact tie refine + collect + bitonic sort
// + derive (+ class bitmap + keep-bitmap zero). One 1024-thread block per batch.
__global__ void __launch_bounds__(1024) k_sel(
    const uint32_t* __restrict__ sw, const uint8_t* __restrict__ cls8,
    const float* __restrict__ pred,
    uint32_t* __restrict__ s_n, float* __restrict__ s_score, float* __restrict__ s_clsf,
    uint32_t* __restrict__ clsbm, float* __restrict__ s_box, float* __restrict__ s_obox,
    uint32_t* __restrict__ keepbm) {
  __shared__ uint64_t sk[KTOP];        // 16 KB
  __shared__ uint32_t hist[NB];        // 32 KB (reused as class bitmap later)
  __shared__ uint32_t seg[64];
  __shared__ uint32_t sh_digit, sh_cnt, sh_k;
  __shared__ uint32_t ncol;
  int b = blockIdx.x, tid = threadIdx.x, lane = tid & 63;
  const uint32_t* swb = sw + (size_t)b * NDET;
  const uint8_t* clb = cls8 + (size_t)b * NDET;
  const uint4* sw4 = (const uint4*)swb;
  if (tid == 0) { sh_k = KTOP; ncol = 0; }
  if (tid < 64) keepbm[b * 64 + tid] = 0;

#define CLEAR_HIST() { __syncthreads(); \
  for (int i = tid; i < NB; i += 1024) hist[i] = 0; \
  __syncthreads(); }

#define FIND() { __syncthreads(); \
  if (tid < 64) { uint32_t s_ = 0; \
    for (int i_ = 0; i_ < NB / 64; ++i_) s_ += hist[tid * (NB / 64) + i_]; \
    seg[tid] = s_; } \
  __syncthreads(); \
  if (tid == 0) { uint32_t k_ = sh_k, cum_ = 0; int S_ = 0; \
    for (; S_ < 63; ++S_) { if (cum_ + seg[S_] >= k_) break; cum_ += seg[S_]; } \
    int d_ = S_ * (NB / 64); \
    for (;; ++d_) { if (cum_ + hist[d_] >= k_) break; cum_ += hist[d_]; } \
    sh_digit = (uint32_t)d_; sh_cnt = hist[d_]; sh_k = k_ - cum_; } \
  __syncthreads(); }

  // ---- pass A: bits [25:13] of (hi - 0x40000000); invalid -> bin 8191 ----
  CLEAR_HIST();
  {
    uint32_t invc = 0;
#define PA(s) { if ((s) == INVHI) ++invc; \
    else atomicAdd(&hist[((s) - 0x40000000u) >> 13], 1u); }
    for (int i = tid; i < NDET / 4; i += 1024) {
      uint4 v = sw4[i];
      PA(v.x) PA(v.y) PA(v.z) PA(v.w)
    }
    if (invc) atomicAdd(&hist[NB - 1], invc);
  }
  FIND();
  uint32_t dA = sh_digit;
  uint32_t sstar, E, r, Lstar = 0xFFFFFFFFu;
  if (dA == NB - 1) {
    sstar = INVHI; E = sh_cnt; r = sh_k;
  } else {
    // ---- pass B: bits [12:0] among prefix dA ----
    CLEAR_HIST();
    for (int i = tid; i < NDET / 4; i += 1024) {
      uint4 v = sw4[i];
#define PB(s) { if ((s) != INVHI && (((s) - 0x40000000u) >> 13) == dA) \
      atomicAdd(&hist[(s) & 0x1FFFu], 1u); }
      PB(v.x) PB(v.y) PB(v.z) PB(v.w)
    }
    FIND();
    sstar = 0x40000000u + (dA << 13) + sh_digit;
    E = sh_cnt; r = sh_k;
  }

  if (r < E) {
    // exact tie refine: r-th smallest low=(n<<7)|cls (22 bits) among hi==sstar.
    CLEAR_HIST();
    for (int n = tid; n < NDET; n += 1024) {
      if (swb[n] == sstar) {
        uint32_t low = ((uint32_t)n << 7) | clb[n];
        atomicAdd(&hist[low >> 11], 1u);
      }
    }
    FIND();
    uint32_t dr0 = sh_digit;
    CLEAR_HIST();
    for (int n = tid; n < NDET; n += 1024) {
      if (swb[n] == sstar) {
        uint32_t low = ((uint32_t)n << 7) | clb[n];
        if ((low >> 11) == dr0) atomicAdd(&hist[low & 0x7FFu], 1u);
      }
    }
    FIND();
    Lstar = (dr0 << 11) | sh_digit;
  }

  // ---- collect exactly KTOP keys ----
  for (int n = tid; n < NDET; n += 1024) {
    uint32_t hi = swb[n];
    uint32_t low = 0;
    bool inc = false;
    if (hi < sstar) inc = true;
    else if (hi == sstar) { low = ((uint32_t)n << 7) | clb[n]; inc = (low <= Lstar); }
    uint64_t ball = __ballot(inc);
    uint32_t bse = 0;
    if (lane == 0) bse = atomicAdd(&ncol, (uint32_t)__popcll(ball));
    bse = __shfl(bse, 0);
    if (inc) {
      if (hi < sstar) low = ((uint32_t)n << 7) | clb[n];
      uint32_t pos = bse + (uint32_t)__popcll(ball & ((1ull << lane) - 1ull));
      if (pos < KTOP) sk[pos] = ((uint64_t)hi << 32) | low;
    }
  }

  // ---- bitonic sort ascending (keys distinct: low contains n) ----
  for (int kk = 2; kk <= KTOP; kk <<= 1) {
    for (int j = kk >> 1; j > 0; j >>= 1) {
      __syncthreads();
      for (int i = tid; i < KTOP; i += 1024) {
        int ixj = i ^ j;
        if (ixj > i) {
          uint64_t a = sk[i], c = sk[ixj];
          bool asc = ((i & kk) == 0);
          if ((a > c) == asc) { sk[i] = c; sk[ixj] = a; }
        }
      }
    }
  }
  __syncthreads();

  // ---- class bitmap (reuse hist space; BMW=5120 <= NB) ----
  uint32_t* bm = hist;
  for (int i = tid; i < BMW; i += 1024) bm[i] = 0;
  __syncthreads();

  // ---- derive arrays ----
  for (int rr = tid; rr < KTOP; rr += 1024) {
    uint64_t key = sk[rr];
    float score = unmono_f32(~(uint32_t)(key >> 32));
    uint32_t low = (uint32_t)key;
    uint32_t n = low >> 7;
    uint32_t cls = low & 127u;
    if (score > 0.0f) atomicOr(&bm[cls * 64 + (rr >> 5)], 1u << (rr & 31));
    const float* p = pred + ((size_t)b * NDET + n) * PREDC;
    float x = p[0], y = p[1], w = p[2], h = p[3];
    float hw = __fmul_rn(w, 0.5f), hh = __fmul_rn(h, 0.5f);
    float x1 = __fsub_rn(x, hw), y1 = __fsub_rn(y, hh);
    float x2 = __fadd_rn(x, hw), y2 = __fadd_rn(y, hh);
    float clsf = (float)cls;
    float off = __fmul_rn(clsf, MAXWH);
    size_t o = (size_t)b * KTOP + rr;
    s_n[o] = n;
    s_score[o] = score;
    s_clsf[o] = clsf;
    s_box[o * 4 + 0] = x1; s_box[o * 4 + 1] = y1;
    s_box[o * 4 + 2] = x2; s_box[o * 4 + 3] = y2;
    s_obox[o * 4 + 0] = __fadd_rn(x1, off); s_obox[o * 4 + 1] = __fadd_rn(y1, off);
    s_obox[o * 4 + 2] = __fadd_rn(x2, off); s_obox[o * 4 + 3] = __fadd_rn(y2, off);
  }
  __syncthreads();
  for (int i = tid; i < BMW; i += 1024) clsbm[(size_t)b * BMW + i] = bm[i];
}

// K3: per-(batch,class) greedy NMS. The global greedy chain decomposes exactly
// into per-class chains (cross-class IoU == 0 < thr). One wave per (b,c);
// IoU expression identical to reference (s_obox, commutative adds) => bit-exact.
__global__ void __launch_bounds__(64) k_cnms(
    const uint32_t* __restrict__ clsbm, const float* __restrict__ s_obox,
    uint32_t* __restrict__ keepbm) {
  __shared__ uint16_t memb[KTOP];                 // 4 KB
  __shared__ float bx1[KTOP], by1[KTOP], bx2[KTOP], by2[KTOP];  // 32 KB
  __shared__ uint64_t aliveM[KTOP / 64];
  int b = blockIdx.x / NCLS, c = blockIdx.x % NCLS;
  int lane = threadIdx.x;
  uint32_t w = clsbm[(size_t)b * BMW + c * 64 + lane];
  int cnt = __popc(w);
  int scan = cnt;
  for (int d = 1; d < 64; d <<= 1) {
    int v = __shfl_up(scan, d);
    if (lane >= d) scan += v;
  }
  int m = __shfl(scan, 63);
  if (m == 0) return;
  int p = scan - cnt;
  uint32_t ww = w;
  while (ww) { int t = __ffs(ww) - 1; ww &= ww - 1; memb[p++] = (uint16_t)(lane * 32 + t); }
  __syncthreads();
  for (int i = lane; i < m; i += 64) {
    const float* bp = s_obox + ((size_t)b * KTOP + memb[i]) * 4;
    bx1[i] = bp[0]; by1[i] = bp[1]; bx2[i] = bp[2]; by2[i] = bp[3];
  }
  __syncthreads();
  int nch = (m + 63) >> 6;
  for (int ch = 0; ch < nch; ++ch) {
    int base = ch * 64;
    int my = base + lane;
    bool has = my < m;
    float ax1 = 0, ay1 = 0, ax2 = 0, ay2 = 0, aarea = 0;
    if (has) {
      ax1 = bx1[my]; ay1 = by1[my]; ax2 = bx2[my]; ay2 = by2[my];
      aarea = __fmul_rn(__fsub_rn(ax2, ax1), __fsub_rn(ay2, ay1));
    }
    bool supp = false;
#define IOU_SUPP(j, guard) { \
      float jx1 = bx1[j], jy1 = by1[j], jx2 = bx2[j], jy2 = by2[j]; \
      float jarea = __fmul_rn(__fsub_rn(jx2, jx1), __fsub_rn(jy2, jy1)); \
      float ltx = fmaxf(jx1, ax1), lty = fmaxf(jy1, ay1); \
      float rbx = fminf(jx2, ax2), rby = fminf(jy2, ay2); \
      float wx = fmaxf(__fsub_rn(rbx, ltx), 0.0f); \
      float wy = fmaxf(__fsub_rn(rby, lty), 0.0f); \
      float inter = __fmul_rn(wx, wy); \
      float denom = __fadd_rn(__fsub_rn(__fadd_rn(jarea, aarea), inter), 1e-7f); \
      float iou = __fdiv_rn(inter, denom); \
      supp = supp || ((guard) && iou > IOU_THR); }
    for (int pc = 0; pc < ch; ++pc) {
      uint64_t aw = aliveM[pc];
      while (aw) {
        int e = __ffsll((unsigned long long)aw) - 1; aw &= aw - 1;
        int j = pc * 64 + e;
        IOU_SUPP(j, has)
      }
    }
    uint64_t sm = __ballot(supp);
    int csz = (m - base >= 64) ? 64 : (m - base);
    for (int d = 0; d < csz; ++d) {
      if (!((sm >> d) & 1ull)) {
        int j = base + d;
        IOU_SUPP(j, (lane > d) && has)
        sm = __ballot(supp);
      }
    }
    uint64_t vmask = (csz == 64) ? ~0ull : ((1ull << csz) - 1ull);
    if (lane == 0) aliveM[ch] = (~sm) & vmask;
    __syncthreads();
    if (has && !supp) {
      int rk = memb[my];
      atomicOr(&keepbm[b * 64 + (rk >> 5)], 1u << (rk & 31));
    }
  }
}

// K4: keep bitmap -> slot src table (rank prefix scan + scatter).
__global__ void __launch_bounds__(64, 1) k_rank(const uint32_t* __restrict__ keepbm,
                                                int* __restrict__ srcTab) {
  int b = blockIdx.x;
  int lane = threadIdx.x;
  uint32_t keep = keepbm[b * 64 + lane];
  int* sb = srcTab + b * MAXDET;
  for (int s = lane; s < MAXDET; s += 64) sb[s] = -1;
  __syncthreads();
  uint32_t cnt = __popc(keep);
  uint32_t scan = cnt;
  for (int d = 1; d < 64; d <<= 1) {
    uint32_t v = __shfl_up(scan, d);
    if (lane >= d) scan += v;
  }
  uint32_t pfx = scan - cnt;
  int lo = lane * 32;
  while (keep) {
    int t = __ffs(keep) - 1;
    keep &= keep - 1;
    if (pfx < MAXDET) sb[pfx] = lo + t;
    ++pfx;
  }
}

// K5: gather + DIRECT write to d_out (PCIe), 16B nontemporal stores, max TLP.
__global__ void __launch_bounds__(256) k_outw(
    const int* __restrict__ srcTab, const uint32_t* __restrict__ s_n,
    const float* __restrict__ s_score, const float* __restrict__ s_clsf,
    const float* __restrict__ s_box, const float* __restrict__ logits,
    fx4* __restrict__ dout) {
  int i = blockIdx.x * 256 + threadIdx.x;
  if (i >= (BATCH * MAXDET * OUTC) / 4) return;
  float v0, v1, v2, v3;
#define GETV(k, dst) { \
    int idx = i * 4 + k; \
    int b = idx / (MAXDET * OUTC); \
    int rem = idx - b * (MAXDET * OUTC); \
    int slot = rem / OUTC; \
    int c = rem - slot * OUTC; \
    int r = srcTab[b * MAXDET + slot]; \
    float x = 0.0f; \
    if (r >= 0) { \
      size_t o = (size_t)b * KTOP + r; \
      if (c < 4) x = s_box[o * 4 + c]; \
      else if (c == 4) x = s_score[o]; \
      else if (c == 5) x = s_clsf[o]; \
      else x = logits[((size_t)b * NDET + s_n[o]) * NCLS + (c - 6)]; \
    } \
    dst = x; }
  GETV(0, v0) GETV(1, v1) GETV(2, v2) GETV(3, v3)
  fx4 f4 = {v0, v1, v2, v3};
  __builtin_nontemporal_store(f4, &dout[i]);
}

extern "C" void kernel_launch(void* const* d_in, const int* in_sizes, int n_in,
                              void* d_out, int out_size, void* d_ws, size_t ws_size,
                              hipStream_t stream) {
  const float* pred = (const float*)d_in[0];
  const float* logits = (const float*)d_in[1];

  char* ws = (char*)d_ws;
  size_t off = 0;
  auto alloc = [&](size_t bytes) -> void* {
    void* p = ws + off;
    off += (bytes + 255) & ~(size_t)255;
    return p;
  };
  uint32_t* sw    = (uint32_t*)alloc((size_t)BATCH * NDET * 4);
  uint8_t*  cls8  = (uint8_t*)alloc((size_t)BATCH * NDET);
  uint32_t* s_n   = (uint32_t*)alloc((size_t)BATCH * KTOP * 4);
  float*    s_sc  = (float*)alloc((size_t)BATCH * KTOP * 4);
  float*    s_cl  = (float*)alloc((size_t)BATCH * KTOP * 4);
  uint32_t* clsbm = (uint32_t*)alloc((size_t)BATCH * BMW * 4);
  float*    s_box = (float*)alloc((size_t)BATCH * KTOP * 16);
  float*    s_ob  = (float*)alloc((size_t)BATCH * KTOP * 16);
  uint32_t* keepb = (uint32_t*)alloc((size_t)BATCH * 64 * 4);
  int*      srcT  = (int*)alloc((size_t)BATCH * MAXDET * 4);
  (void)ws_size; (void)in_sizes; (void)n_in;

  k_keys<<<(BATCH * NDET) / 256, 256, 0, stream>>>(pred, sw, cls8);
  k_sel<<<BATCH, 1024, 0, stream>>>(sw, cls8, pred, s_n, s_sc, s_cl, clsbm, s_box, s_ob, keepb);
  k_cnms<<<BATCH * NCLS, 64, 0, stream>>>(clsbm, s_ob, keepb);
  k_rank<<<BATCH, 64, 0, stream>>>(keepb, srcT);
  int n4 = (BATCH * MAXDET * OUTC) / 4;
  k_outw<<<(n4 + 255) / 256, 256, 0, stream>>>(srcT, s_n, s_sc, s_cl, s_box, logits, (fx4*)d_out);
}

// Round 14
// 115.778 us; speedup vs baseline: 1.6271x; 1.0178x over previous
//
#include <hip/hip_runtime.h>
#include <stdint.h>

#define BATCH 16
#define NDET 25200
#define NCLS 80
#define PREDC 85
#define KTOP 2048
#define MAXDET 300
#define OUTC 86
#define CONF_THR 0.4f
#define IOU_THR 0.45f
#define MAXWH 4096.0f
#define INVHI 0xBF800000u       // ~mono(-1.0f): score word of invalid rows
#define BMW (NCLS * 64)         // class bitmap words per batch (80 classes x 64)
#define NB 8192                 // flat histogram bins
#define QPB ((MAXDET * OUTC) / 4)   // 6450 float4 per batch
#define BPB ((QPB + 255) / 256)     // 26 blocks per batch

typedef float fx4 __attribute__((ext_vector_type(4)));

// ---- monotone float<->uint mapping (ascending) ----
__device__ __forceinline__ uint32_t mono_f32(float f) {
  uint32_t u = __float_as_uint(f);
  return (u & 0x80000000u) ? ~u : (u | 0x80000000u);
}
__device__ __forceinline__ float unmono_f32(uint32_t m) {
  uint32_t u = (m & 0x80000000u) ? (m & 0x7FFFFFFFu) : ~m;
  return __uint_as_float(u);
}

// K1: LDS-staged coalesced score/argmax (4 lanes/row, exact first-max tie-break).
__global__ void __launch_bounds__(256) k_keys(const float* __restrict__ pred,
                                              uint32_t* __restrict__ sw,
                                              uint8_t* __restrict__ cls8) {
  __shared__ float lds[64 * PREDC];   // 21760 B
  int blk = blockIdx.x, tid = threadIdx.x;
  int q = tid & 3, r = tid >> 2;      // r in 0..63
  for (int ch = 0; ch < 4; ++ch) {
    __syncthreads();
    const float4* src4 = (const float4*)(pred + ((size_t)blk * 256 + (size_t)ch * 64) * PREDC);
    float4* l4 = (float4*)lds;
    for (int i = tid; i < (64 * PREDC) / 4; i += 256) l4[i] = src4[i];
    __syncthreads();
    const float* row = lds + r * PREDC;
    float obj = row[4];
    float best = -1e30f; int bc = 0;
    if (obj > CONF_THR) {
      for (int k = 0; k < 20; ++k) {
        int c = q + 4 * k;
        float s = __fmul_rn(row[5 + c], obj);   // single-rounded, no contraction
        if (s > best) { best = s; bc = c; }
      }
    }
    for (int d = 1; d <= 2; d <<= 1) {
      float vo = __shfl_xor(best, d);
      int co = __shfl_xor(bc, d);
      if (vo > best || (vo == best && co < bc)) { best = vo; bc = co; }
    }
    if (q == 0) {
      float score = -1.0f; uint32_t cl = 0;
      if (obj > CONF_THR && best > CONF_THR) { score = best; cl = (uint32_t)bc; }
      int rowIdx = blk * 256 + ch * 64 + r;
      sw[rowIdx] = ~mono_f32(score);
      cls8[rowIdx] = (uint8_t)cl;
    }
  }
}

// K2: fused radix-select (2x13-bit) + exact tie refine + collect + bitonic sort
// + derive (+ class bitmap + keep-bitmap zero). One 1024-thread block per batch.
__global__ void __launch_bounds__(1024) k_sel(
    const uint32_t* __restrict__ sw, const uint8_t* __restrict__ cls8,
    const float* __restrict__ pred,
    uint32_t* __restrict__ s_n, float* __restrict__ s_score, float* __restrict__ s_clsf,
    uint32_t* __restrict__ clsbm, float* __restrict__ s_box, float* __restrict__ s_obox,
    uint32_t* __restrict__ keepbm) {
  __shared__ uint64_t sk[KTOP];        // 16 KB
  __shared__ uint32_t hist[NB];        // 32 KB (reused as class bitmap later)
  __shared__ uint32_t seg[64];
  __shared__ uint32_t sh_digit, sh_cnt, sh_k;
  __shared__ uint32_t ncol;
  int b = blockIdx.x, tid = threadIdx.x, lane = tid & 63;
  const uint32_t* swb = sw + (size_t)b * NDET;
  const uint8_t* clb = cls8 + (size_t)b * NDET;
  const uint4* sw4 = (const uint4*)swb;
  if (tid == 0) { sh_k = KTOP; ncol = 0; }
  if (tid < 64) keepbm[b * 64 + tid] = 0;

#define CLEAR_HIST() { __syncthreads(); \
  for (int i = tid; i < NB; i += 1024) hist[i] = 0; \
  __syncthreads(); }

#define FIND() { __syncthreads(); \
  if (tid < 64) { uint32_t s_ = 0; \
    for (int i_ = 0; i_ < NB / 64; ++i_) s_ += hist[tid * (NB / 64) + i_]; \
    seg[tid] = s_; } \
  __syncthreads(); \
  if (tid == 0) { uint32_t k_ = sh_k, cum_ = 0; int S_ = 0; \
    for (; S_ < 63; ++S_) { if (cum_ + seg[S_] >= k_) break; cum_ += seg[S_]; } \
    int d_ = S_ * (NB / 64); \
    for (;; ++d_) { if (cum_ + hist[d_] >= k_) break; cum_ += hist[d_]; } \
    sh_digit = (uint32_t)d_; sh_cnt = hist[d_]; sh_k = k_ - cum_; } \
  __syncthreads(); }

  // ---- pass A: bits [25:13] of (hi - 0x40000000); invalid -> bin 8191 ----
  CLEAR_HIST();
  {
    uint32_t invc = 0;
#define PA(s) { if ((s) == INVHI) ++invc; \
    else atomicAdd(&hist[((s) - 0x40000000u) >> 13], 1u); }
    for (int i = tid; i < NDET / 4; i += 1024) {
      uint4 v = sw4[i];
      PA(v.x) PA(v.y) PA(v.z) PA(v.w)
    }
    if (invc) atomicAdd(&hist[NB - 1], invc);
  }
  FIND();
  uint32_t dA = sh_digit;
  uint32_t sstar, E, r, Lstar = 0xFFFFFFFFu;
  if (dA == NB - 1) {
    sstar = INVHI; E = sh_cnt; r = sh_k;
  } else {
    // ---- pass B: bits [12:0] among prefix dA ----
    CLEAR_HIST();
    for (int i = tid; i < NDET / 4; i += 1024) {
      uint4 v = sw4[i];
#define PB(s) { if ((s) != INVHI && (((s) - 0x40000000u) >> 13) == dA) \
      atomicAdd(&hist[(s) & 0x1FFFu], 1u); }
      PB(v.x) PB(v.y) PB(v.z) PB(v.w)
    }
    FIND();
    sstar = 0x40000000u + (dA << 13) + sh_digit;
    E = sh_cnt; r = sh_k;
  }

  if (r < E) {
    // exact tie refine: r-th smallest low=(n<<7)|cls (22 bits) among hi==sstar.
    CLEAR_HIST();
    for (int n = tid; n < NDET; n += 1024) {
      if (swb[n] == sstar) {
        uint32_t low = ((uint32_t)n << 7) | clb[n];
        atomicAdd(&hist[low >> 11], 1u);
      }
    }
    FIND();
    uint32_t dr0 = sh_digit;
    CLEAR_HIST();
    for (int n = tid; n < NDET; n += 1024) {
      if (swb[n] == sstar) {
        uint32_t low = ((uint32_t)n << 7) | clb[n];
        if ((low >> 11) == dr0) atomicAdd(&hist[low & 0x7FFu], 1u);
      }
    }
    FIND();
    Lstar = (dr0 << 11) | sh_digit;
  }

  // ---- collect exactly KTOP keys ----
  for (int n = tid; n < NDET; n += 1024) {
    uint32_t hi = swb[n];
    uint32_t low = 0;
    bool inc = false;
    if (hi < sstar) inc = true;
    else if (hi == sstar) { low = ((uint32_t)n << 7) | clb[n]; inc = (low <= Lstar); }
    uint64_t ball = __ballot(inc);
    uint32_t bse = 0;
    if (lane == 0) bse = atomicAdd(&ncol, (uint32_t)__popcll(ball));
    bse = __shfl(bse, 0);
    if (inc) {
      if (hi < sstar) low = ((uint32_t)n << 7) | clb[n];
      uint32_t pos = bse + (uint32_t)__popcll(ball & ((1ull << lane) - 1ull));
      if (pos < KTOP) sk[pos] = ((uint64_t)hi << 32) | low;
    }
  }

  // ---- bitonic sort ascending (keys distinct: low contains n) ----
  for (int kk = 2; kk <= KTOP; kk <<= 1) {
    for (int j = kk >> 1; j > 0; j >>= 1) {
      __syncthreads();
      for (int i = tid; i < KTOP; i += 1024) {
        int ixj = i ^ j;
        if (ixj > i) {
          uint64_t a = sk[i], c = sk[ixj];
          bool asc = ((i & kk) == 0);
          if ((a > c) == asc) { sk[i] = c; sk[ixj] = a; }
        }
      }
    }
  }
  __syncthreads();

  // ---- class bitmap (reuse hist space; BMW=5120 <= NB) ----
  uint32_t* bm = hist;
  for (int i = tid; i < BMW; i += 1024) bm[i] = 0;
  __syncthreads();

  // ---- derive arrays ----
  for (int rr = tid; rr < KTOP; rr += 1024) {
    uint64_t key = sk[rr];
    float score = unmono_f32(~(uint32_t)(key >> 32));
    uint32_t low = (uint32_t)key;
    uint32_t n = low >> 7;
    uint32_t cls = low & 127u;
    if (score > 0.0f) atomicOr(&bm[cls * 64 + (rr >> 5)], 1u << (rr & 31));
    const float* p = pred + ((size_t)b * NDET + n) * PREDC;
    float x = p[0], y = p[1], w = p[2], h = p[3];
    float hw = __fmul_rn(w, 0.5f), hh = __fmul_rn(h, 0.5f);
    float x1 = __fsub_rn(x, hw), y1 = __fsub_rn(y, hh);
    float x2 = __fadd_rn(x, hw), y2 = __fadd_rn(y, hh);
    float clsf = (float)cls;
    float off = __fmul_rn(clsf, MAXWH);
    size_t o = (size_t)b * KTOP + rr;
    s_n[o] = n;
    s_score[o] = score;
    s_clsf[o] = clsf;
    s_box[o * 4 + 0] = x1; s_box[o * 4 + 1] = y1;
    s_box[o * 4 + 2] = x2; s_box[o * 4 + 3] = y2;
    s_obox[o * 4 + 0] = __fadd_rn(x1, off); s_obox[o * 4 + 1] = __fadd_rn(y1, off);
    s_obox[o * 4 + 2] = __fadd_rn(x2, off); s_obox[o * 4 + 3] = __fadd_rn(y2, off);
  }
  __syncthreads();
  for (int i = tid; i < BMW; i += 1024) clsbm[(size_t)b * BMW + i] = bm[i];
}

// K3: per-(batch,class) greedy NMS (exact decomposition: cross-class IoU == 0).
__global__ void __launch_bounds__(64) k_cnms(
    const uint32_t* __restrict__ clsbm, const float* __restrict__ s_obox,
    uint32_t* __restrict__ keepbm) {
  __shared__ uint16_t memb[KTOP];                 // 4 KB
  __shared__ float bx1[KTOP], by1[KTOP], bx2[KTOP], by2[KTOP];  // 32 KB
  __shared__ uint64_t aliveM[KTOP / 64];
  int b = blockIdx.x / NCLS, c = blockIdx.x % NCLS;
  int lane = threadIdx.x;
  uint32_t w = clsbm[(size_t)b * BMW + c * 64 + lane];
  int cnt = __popc(w);
  int scan = cnt;
  for (int d = 1; d < 64; d <<= 1) {
    int v = __shfl_up(scan, d);
    if (lane >= d) scan += v;
  }
  int m = __shfl(scan, 63);
  if (m == 0) return;
  int p = scan - cnt;
  uint32_t ww = w;
  while (ww) { int t = __ffs(ww) - 1; ww &= ww - 1; memb[p++] = (uint16_t)(lane * 32 + t); }
  __syncthreads();
  for (int i = lane; i < m; i += 64) {
    const float* bp = s_obox + ((size_t)b * KTOP + memb[i]) * 4;
    bx1[i] = bp[0]; by1[i] = bp[1]; bx2[i] = bp[2]; by2[i] = bp[3];
  }
  __syncthreads();
  int nch = (m + 63) >> 6;
  for (int ch = 0; ch < nch; ++ch) {
    int base = ch * 64;
    int my = base + lane;
    bool has = my < m;
    float ax1 = 0, ay1 = 0, ax2 = 0, ay2 = 0, aarea = 0;
    if (has) {
      ax1 = bx1[my]; ay1 = by1[my]; ax2 = bx2[my]; ay2 = by2[my];
      aarea = __fmul_rn(__fsub_rn(ax2, ax1), __fsub_rn(ay2, ay1));
    }
    bool supp = false;
#define IOU_SUPP(j, guard) { \
      float jx1 = bx1[j], jy1 = by1[j], jx2 = bx2[j], jy2 = by2[j]; \
      float jarea = __fmul_rn(__fsub_rn(jx2, jx1), __fsub_rn(jy2, jy1)); \
      float ltx = fmaxf(jx1, ax1), lty = fmaxf(jy1, ay1); \
      float rbx = fminf(jx2, ax2), rby = fminf(jy2, ay2); \
      float wx = fmaxf(__fsub_rn(rbx, ltx), 0.0f); \
      float wy = fmaxf(__fsub_rn(rby, lty), 0.0f); \
      float inter = __fmul_rn(wx, wy); \
      float denom = __fadd_rn(__fsub_rn(__fadd_rn(jarea, aarea), inter), 1e-7f); \
      float iou = __fdiv_rn(inter, denom); \
      supp = supp || ((guard) && iou > IOU_THR); }
    for (int pc = 0; pc < ch; ++pc) {
      uint64_t aw = aliveM[pc];
      while (aw) {
        int e = __ffsll((unsigned long long)aw) - 1; aw &= aw - 1;
        int j = pc * 64 + e;
        IOU_SUPP(j, has)
      }
    }
    uint64_t sm = __ballot(supp);
    int csz = (m - base >= 64) ? 64 : (m - base);
    for (int d = 0; d < csz; ++d) {
      if (!((sm >> d) & 1ull)) {
        int j = base + d;
        IOU_SUPP(j, (lane > d) && has)
        sm = __ballot(supp);
      }
    }
    uint64_t vmask = (csz == 64) ? ~0ull : ((1ull << csz) - 1ull);
    if (lane == 0) aliveM[ch] = (~sm) & vmask;
    __syncthreads();
    if (has && !supp) {
      int rk = memb[my];
      atomicOr(&keepbm[b * 64 + (rk >> 5)], 1u << (rk & 31));
    }
  }
}

// K4: gather + DIRECT write to d_out. Per-batch blocks; slot->rank table
// rebuilt in LDS from keepbm (fused former k_rank; redundant per block but
// ~200 cycles). 16B nontemporal stores, max outstanding writes.
__global__ void __launch_bounds__(256) k_outw(
    const uint32_t* __restrict__ keepbm, const uint32_t* __restrict__ s_n,
    const float* __restrict__ s_score, const float* __restrict__ s_clsf,
    const float* __restrict__ s_box, const float* __restrict__ logits,
    fx4* __restrict__ dout) {
  __shared__ int src[MAXDET];
  int b = blockIdx.x / BPB;
  int jb = blockIdx.x % BPB;
  int tid = threadIdx.x;
  for (int s = tid; s < MAXDET; s += 256) src[s] = -1;
  __syncthreads();
  if (tid < 64) {
    uint32_t keep = keepbm[b * 64 + tid];
    uint32_t cnt = __popc(keep);
    uint32_t scan = cnt;
    for (int d = 1; d < 64; d <<= 1) {
      uint32_t v = __shfl_up(scan, d);
      if (tid >= d) scan += v;
    }
    uint32_t pfx = scan - cnt;
    int lo = tid * 32;
    while (keep) {
      int t = __ffs(keep) - 1;
      keep &= keep - 1;
      if (pfx < MAXDET) src[pfx] = lo + t;
      ++pfx;
    }
  }
  __syncthreads();
  int i = jb * 256 + tid;          // quad index within batch
  if (i >= QPB) return;
  float v0, v1, v2, v3;
#define GETV(k, dst) { \
    int idx = i * 4 + k; \
    int slot = idx / OUTC; \
    int c = idx - slot * OUTC; \
    int r = src[slot]; \
    float x = 0.0f; \
    if (r >= 0) { \
      size_t o = (size_t)b * KTOP + r; \
      if (c < 4) x = s_box[o * 4 + c]; \
      else if (c == 4) x = s_score[o]; \
      else if (c == 5) x = s_clsf[o]; \
      else x = logits[((size_t)b * NDET + s_n[o]) * NCLS + (c - 6)]; \
    } \
    dst = x; }
  GETV(0, v0) GETV(1, v1) GETV(2, v2) GETV(3, v3)
  fx4 f4 = {v0, v1, v2, v3};
  __builtin_nontemporal_store(f4, &dout[(size_t)b * QPB + i]);
}

extern "C" void kernel_launch(void* const* d_in, const int* in_sizes, int n_in,
                              void* d_out, int out_size, void* d_ws, size_t ws_size,
                              hipStream_t stream) {
  const float* pred = (const float*)d_in[0];
  const float* logits = (const float*)d_in[1];

  char* ws = (char*)d_ws;
  size_t off = 0;
  auto alloc = [&](size_t bytes) -> void* {
    void* p = ws + off;
    off += (bytes + 255) & ~(size_t)255;
    return p;
  };
  uint32_t* sw    = (uint32_t*)alloc((size_t)BATCH * NDET * 4);
  uint8_t*  cls8  = (uint8_t*)alloc((size_t)BATCH * NDET);
  uint32_t* s_n   = (uint32_t*)alloc((size_t)BATCH * KTOP * 4);
  float*    s_sc  = (float*)alloc((size_t)BATCH * KTOP * 4);
  float*    s_cl  = (float*)alloc((size_t)BATCH * KTOP * 4);
  uint32_t* clsbm = (uint32_t*)alloc((size_t)BATCH * BMW * 4);
  float*    s_box = (float*)alloc((size_t)BATCH * KTOP * 16);
  float*    s_ob  = (float*)alloc((size_t)BATCH * KTOP * 16);
  uint32_t* keepb = (uint32_t*)alloc((size_t)BATCH * 64 * 4);
  (void)ws_size; (void)in_sizes; (void)n_in;

  k_keys<<<(BATCH * NDET) / 256, 256, 0, stream>>>(pred, sw, cls8);
  k_sel<<<BATCH, 1024, 0, stream>>>(sw, cls8, pred, s_n, s_sc, s_cl, clsbm, s_box, s_ob, keepb);
  k_cnms<<<BATCH * NCLS, 64, 0, stream>>>(clsbm, s_ob, keepb);
  k_outw<<<BATCH * BPB, 256, 0, stream>>>(keepb, s_n, s_sc, s_cl, s_box, logits, (fx4*)d_out);
}

// Round 15
// 109.002 us; speedup vs baseline: 1.7283x; 1.0622x over previous
//
#include <hip/hip_runtime.h>
#include <stdint.h>

#define BATCH 16
#define NDET 25200
#define NCLS 80
#define PREDC 85
#define KTOP 2048
#define MAXDET 300
#define OUTC 86
#define CONF_THR 0.4f
#define IOU_THR 0.45f
#define MAXWH 4096.0f
#define INVHI 0xBF800000u       // ~mono(-1.0f): score word of invalid rows
#define BMW (NCLS * 64)         // class bitmap words per batch (80 classes x 64)
#define NB 8192                 // flat histogram bins
#define QPB ((MAXDET * OUTC) / 4)   // 6450 float4 per batch
#define BPB ((QPB + 255) / 256)     // 26 blocks per batch

typedef float fx4 __attribute__((ext_vector_type(4)));

// ---- monotone float<->uint mapping (ascending) ----
__device__ __forceinline__ uint32_t mono_f32(float f) {
  uint32_t u = __float_as_uint(f);
  return (u & 0x80000000u) ? ~u : (u | 0x80000000u);
}
__device__ __forceinline__ float unmono_f32(uint32_t m) {
  uint32_t u = (m & 0x80000000u) ? (m & 0x7FFFFFFFu) : ~m;
  return __uint_as_float(u);
}

// K1: obj-gated score/argmax, quad (4 lanes) per row. ~60% of rows fail
// obj>0.4 and skip their 320B of class floats entirely (round-14 theory:
// fetch 137->~90MB). In-lane class order ascending (strict > = first max);
// cross-lane combine prefers higher val then lower class — exact jnp.argmax.
__global__ void __launch_bounds__(256) k_keys(const float* __restrict__ pred,
                                              uint32_t* __restrict__ sw,
                                              uint8_t* __restrict__ cls8) {
  int gq = blockIdx.x * 64 + (threadIdx.x >> 2);   // 64 rows per block
  int q = threadIdx.x & 3;
  const float* row = pred + (size_t)gq * PREDC;
  float obj = row[4];
  float score = -1.0f;
  uint32_t cl = 0;
  if (obj > CONF_THR) {
    float best = -1e30f;
    int bc = 0;
#pragma unroll
    for (int k = 0; k < 5; ++k) {
#pragma unroll
      for (int j = 0; j < 4; ++j) {
        int c = k * 16 + q * 4 + j;                 // ascending within lane
        float s = __fmul_rn(row[5 + c], obj);       // single-rounded, no contraction
        if (s > best) { best = s; bc = c; }         // strict > : first max
      }
    }
    for (int d = 1; d <= 2; d <<= 1) {              // quad reduce (uniform per quad)
      float vo = __shfl_xor(best, d);
      int co = __shfl_xor(bc, d);
      if (vo > best || (vo == best && co < bc)) { best = vo; bc = co; }
    }
    if (best > CONF_THR) { score = best; cl = (uint32_t)bc; }
  }
  if (q == 0) {
    sw[gq] = ~mono_f32(score);
    cls8[gq] = (uint8_t)cl;
  }
}

// K2: fused radix-select (2x13-bit) + exact tie refine + collect + bitonic sort
// + derive (+ class bitmap + keep-bitmap zero). One 1024-thread block per batch.
__global__ void __launch_bounds__(1024) k_sel(
    const uint32_t* __restrict__ sw, const uint8_t* __restrict__ cls8,
    const float* __restrict__ pred,
    uint32_t* __restrict__ s_n, float* __restrict__ s_score, float* __restrict__ s_clsf,
    uint32_t* __restrict__ clsbm, float* __restrict__ s_box, float* __restrict__ s_obox,
    uint32_t* __restrict__ keepbm) {
  __shared__ uint64_t sk[KTOP];        // 16 KB
  __shared__ uint32_t hist[NB];        // 32 KB (reused as class bitmap later)
  __shared__ uint32_t seg[64];
  __shared__ uint32_t sh_digit, sh_cnt, sh_k;
  __shared__ uint32_t ncol;
  int b = blockIdx.x, tid = threadIdx.x, lane = tid & 63;
  const uint32_t* swb = sw + (size_t)b * NDET;
  const uint8_t* clb = cls8 + (size_t)b * NDET;
  const uint4* sw4 = (const uint4*)swb;
  if (tid == 0) { sh_k = KTOP; ncol = 0; }
  if (tid < 64) keepbm[b * 64 + tid] = 0;

#define CLEAR_HIST() { __syncthreads(); \
  for (int i = tid; i < NB; i += 1024) hist[i] = 0; \
  __syncthreads(); }

#define FIND() { __syncthreads(); \
  if (tid < 64) { uint32_t s_ = 0; \
    for (int i_ = 0; i_ < NB / 64; ++i_) s_ += hist[tid * (NB / 64) + i_]; \
    seg[tid] = s_; } \
  __syncthreads(); \
  if (tid == 0) { uint32_t k_ = sh_k, cum_ = 0; int S_ = 0; \
    for (; S_ < 63; ++S_) { if (cum_ + seg[S_] >= k_) break; cum_ += seg[S_]; } \
    int d_ = S_ * (NB / 64); \
    for (;; ++d_) { if (cum_ + hist[d_] >= k_) break; cum_ += hist[d_]; } \
    sh_digit = (uint32_t)d_; sh_cnt = hist[d_]; sh_k = k_ - cum_; } \
  __syncthreads(); }

  // ---- pass A: bits [25:13] of (hi - 0x40000000); invalid -> bin 8191 ----
  CLEAR_HIST();
  {
    uint32_t invc = 0;
#define PA(s) { if ((s) == INVHI) ++invc; \
    else atomicAdd(&hist[((s) - 0x40000000u) >> 13], 1u); }
    for (int i = tid; i < NDET / 4; i += 1024) {
      uint4 v = sw4[i];
      PA(v.x) PA(v.y) PA(v.z) PA(v.w)
    }
    if (invc) atomicAdd(&hist[NB - 1], invc);
  }
  FIND();
  uint32_t dA = sh_digit;
  uint32_t sstar, E, r, Lstar = 0xFFFFFFFFu;
  if (dA == NB - 1) {
    sstar = INVHI; E = sh_cnt; r = sh_k;
  } else {
    // ---- pass B: bits [12:0] among prefix dA ----
    CLEAR_HIST();
    for (int i = tid; i < NDET / 4; i += 1024) {
      uint4 v = sw4[i];
#define PB(s) { if ((s) != INVHI && (((s) - 0x40000000u) >> 13) == dA) \
      atomicAdd(&hist[(s) & 0x1FFFu], 1u); }
      PB(v.x) PB(v.y) PB(v.z) PB(v.w)
    }
    FIND();
    sstar = 0x40000000u + (dA << 13) + sh_digit;
    E = sh_cnt; r = sh_k;
  }

  if (r < E) {
    // exact tie refine: r-th smallest low=(n<<7)|cls (22 bits) among hi==sstar.
    CLEAR_HIST();
    for (int n = tid; n < NDET; n += 1024) {
      if (swb[n] == sstar) {
        uint32_t low = ((uint32_t)n << 7) | clb[n];
        atomicAdd(&hist[low >> 11], 1u);
      }
    }
    FIND();
    uint32_t dr0 = sh_digit;
    CLEAR_HIST();
    for (int n = tid; n < NDET; n += 1024) {
      if (swb[n] == sstar) {
        uint32_t low = ((uint32_t)n << 7) | clb[n];
        if ((low >> 11) == dr0) atomicAdd(&hist[low & 0x7FFu], 1u);
      }
    }
    FIND();
    Lstar = (dr0 << 11) | sh_digit;
  }

  // ---- collect exactly KTOP keys ----
  for (int n = tid; n < NDET; n += 1024) {
    uint32_t hi = swb[n];
    uint32_t low = 0;
    bool inc = false;
    if (hi < sstar) inc = true;
    else if (hi == sstar) { low = ((uint32_t)n << 7) | clb[n]; inc = (low <= Lstar); }
    uint64_t ball = __ballot(inc);
    uint32_t bse = 0;
    if (lane == 0) bse = atomicAdd(&ncol, (uint32_t)__popcll(ball));
    bse = __shfl(bse, 0);
    if (inc) {
      if (hi < sstar) low = ((uint32_t)n << 7) | clb[n];
      uint32_t pos = bse + (uint32_t)__popcll(ball & ((1ull << lane) - 1ull));
      if (pos < KTOP) sk[pos] = ((uint64_t)hi << 32) | low;
    }
  }

  // ---- bitonic sort ascending (keys distinct: low contains n) ----
  for (int kk = 2; kk <= KTOP; kk <<= 1) {
    for (int j = kk >> 1; j > 0; j >>= 1) {
      __syncthreads();
      for (int i = tid; i < KTOP; i += 1024) {
        int ixj = i ^ j;
        if (ixj > i) {
          uint64_t a = sk[i], c = sk[ixj];
          bool asc = ((i & kk) == 0);
          if ((a > c) == asc) { sk[i] = c; sk[ixj] = a; }
        }
      }
    }
  }
  __syncthreads();

  // ---- class bitmap (reuse hist space; BMW=5120 <= NB) ----
  uint32_t* bm = hist;
  for (int i = tid; i < BMW; i += 1024) bm[i] = 0;
  __syncthreads();

  // ---- derive arrays ----
  for (int rr = tid; rr < KTOP; rr += 1024) {
    uint64_t key = sk[rr];
    float score = unmono_f32(~(uint32_t)(key >> 32));
    uint32_t low = (uint32_t)key;
    uint32_t n = low >> 7;
    uint32_t cls = low & 127u;
    if (score > 0.0f) atomicOr(&bm[cls * 64 + (rr >> 5)], 1u << (rr & 31));
    const float* p = pred + ((size_t)b * NDET + n) * PREDC;
    float x = p[0], y = p[1], w = p[2], h = p[3];
    float hw = __fmul_rn(w, 0.5f), hh = __fmul_rn(h, 0.5f);
    float x1 = __fsub_rn(x, hw), y1 = __fsub_rn(y, hh);
    float x2 = __fadd_rn(x, hw), y2 = __fadd_rn(y, hh);
    float clsf = (float)cls;
    float off = __fmul_rn(clsf, MAXWH);
    size_t o = (size_t)b * KTOP + rr;
    s_n[o] = n;
    s_score[o] = score;
    s_clsf[o] = clsf;
    s_box[o * 4 + 0] = x1; s_box[o * 4 + 1] = y1;
    s_box[o * 4 + 2] = x2; s_box[o * 4 + 3] = y2;
    s_obox[o * 4 + 0] = __fadd_rn(x1, off); s_obox[o * 4 + 1] = __fadd_rn(y1, off);
    s_obox[o * 4 + 2] = __fadd_rn(x2, off); s_obox[o * 4 + 3] = __fadd_rn(y2, off);
  }
  __syncthreads();
  for (int i = tid; i < BMW; i += 1024) clsbm[(size_t)b * BMW + i] = bm[i];
}

// K3: per-(batch,class) greedy NMS (exact decomposition: cross-class IoU == 0).
__global__ void __launch_bounds__(64) k_cnms(
    const uint32_t* __restrict__ clsbm, const float* __restrict__ s_obox,
    uint32_t* __restrict__ keepbm) {
  __shared__ uint16_t memb[KTOP];                 // 4 KB
  __shared__ float bx1[KTOP], by1[KTOP], bx2[KTOP], by2[KTOP];  // 32 KB
  __shared__ uint64_t aliveM[KTOP / 64];
  int b = blockIdx.x / NCLS, c = blockIdx.x % NCLS;
  int lane = threadIdx.x;
  uint32_t w = clsbm[(size_t)b * BMW + c * 64 + lane];
  int cnt = __popc(w);
  int scan = cnt;
  for (int d = 1; d < 64; d <<= 1) {
    int v = __shfl_up(scan, d);
    if (lane >= d) scan += v;
  }
  int m = __shfl(scan, 63);
  if (m == 0) return;
  int p = scan - cnt;
  uint32_t ww = w;
  while (ww) { int t = __ffs(ww) - 1; ww &= ww - 1; memb[p++] = (uint16_t)(lane * 32 + t); }
  __syncthreads();
  for (int i = lane; i < m; i += 64) {
    const float* bp = s_obox + ((size_t)b * KTOP + memb[i]) * 4;
    bx1[i] = bp[0]; by1[i] = bp[1]; bx2[i] = bp[2]; by2[i] = bp[3];
  }
  __syncthreads();
  int nch = (m + 63) >> 6;
  for (int ch = 0; ch < nch; ++ch) {
    int base = ch * 64;
    int my = base + lane;
    bool has = my < m;
    float ax1 = 0, ay1 = 0, ax2 = 0, ay2 = 0, aarea = 0;
    if (has) {
      ax1 = bx1[my]; ay1 = by1[my]; ax2 = bx2[my]; ay2 = by2[my];
      aarea = __fmul_rn(__fsub_rn(ax2, ax1), __fsub_rn(ay2, ay1));
    }
    bool supp = false;
#define IOU_SUPP(j, guard) { \
      float jx1 = bx1[j], jy1 = by1[j], jx2 = bx2[j], jy2 = by2[j]; \
      float jarea = __fmul_rn(__fsub_rn(jx2, jx1), __fsub_rn(jy2, jy1)); \
      float ltx = fmaxf(jx1, ax1), lty = fmaxf(jy1, ay1); \
      float rbx = fminf(jx2, ax2), rby = fminf(jy2, ay2); \
      float wx = fmaxf(__fsub_rn(rbx, ltx), 0.0f); \
      float wy = fmaxf(__fsub_rn(rby, lty), 0.0f); \
      float inter = __fmul_rn(wx, wy); \
      float denom = __fadd_rn(__fsub_rn(__fadd_rn(jarea, aarea), inter), 1e-7f); \
      float iou = __fdiv_rn(inter, denom); \
      supp = supp || ((guard) && iou > IOU_THR); }
    for (int pc = 0; pc < ch; ++pc) {
      uint64_t aw = aliveM[pc];
      while (aw) {
        int e = __ffsll((unsigned long long)aw) - 1; aw &= aw - 1;
        int j = pc * 64 + e;
        IOU_SUPP(j, has)
      }
    }
    uint64_t sm = __ballot(supp);
    int csz = (m - base >= 64) ? 64 : (m - base);
    for (int d = 0; d < csz; ++d) {
      if (!((sm >> d) & 1ull)) {
        int j = base + d;
        IOU_SUPP(j, (lane > d) && has)
        sm = __ballot(supp);
      }
    }
    uint64_t vmask = (csz == 64) ? ~0ull : ((1ull << csz) - 1ull);
    if (lane == 0) aliveM[ch] = (~sm) & vmask;
    __syncthreads();
    if (has && !supp) {
      int rk = memb[my];
      atomicOr(&keepbm[b * 64 + (rk >> 5)], 1u << (rk & 31));
    }
  }
}

// K4: gather + DIRECT write to d_out. Per-batch blocks; slot->rank table
// rebuilt in LDS from keepbm. 16B nontemporal stores, max outstanding writes.
__global__ void __launch_bounds__(256) k_outw(
    const uint32_t* __restrict__ keepbm, const uint32_t* __restrict__ s_n,
    const float* __restrict__ s_score, const float* __restrict__ s_clsf,
    const float* __restrict__ s_box, const float* __restrict__ logits,
    fx4* __restrict__ dout) {
  __shared__ int src[MAXDET];
  int b = blockIdx.x / BPB;
  int jb = blockIdx.x % BPB;
  int tid = threadIdx.x;
  for (int s = tid; s < MAXDET; s += 256) src[s] = -1;
  __syncthreads();
  if (tid < 64) {
    uint32_t keep = keepbm[b * 64 + tid];
    uint32_t cnt = __popc(keep);
    uint32_t scan = cnt;
    for (int d = 1; d < 64; d <<= 1) {
      uint32_t v = __shfl_up(scan, d);
      if (tid >= d) scan += v;
    }
    uint32_t pfx = scan - cnt;
    int lo = tid * 32;
    while (keep) {
      int t = __ffs(keep) - 1;
      keep &= keep - 1;
      if (pfx < MAXDET) src[pfx] = lo + t;
      ++pfx;
    }
  }
  __syncthreads();
  int i = jb * 256 + tid;          // quad index within batch
  if (i >= QPB) return;
  float v0, v1, v2, v3;
#define GETV(k, dst) { \
    int idx = i * 4 + k; \
    int slot = idx / OUTC; \
    int c = idx - slot * OUTC; \
    int r = src[slot]; \
    float x = 0.0f; \
    if (r >= 0) { \
      size_t o = (size_t)b * KTOP + r; \
      if (c < 4) x = s_box[o * 4 + c]; \
      else if (c == 4) x = s_score[o]; \
      else if (c == 5) x = s_clsf[o]; \
      else x = logits[((size_t)b * NDET + s_n[o]) * NCLS + (c - 6)]; \
    } \
    dst = x; }
  GETV(0, v0) GETV(1, v1) GETV(2, v2) GETV(3, v3)
  fx4 f4 = {v0, v1, v2, v3};
  __builtin_nontemporal_store(f4, &dout[(size_t)b * QPB + i]);
}

extern "C" void kernel_launch(void* const* d_in, const int* in_sizes, int n_in,
                              void* d_out, int out_size, void* d_ws, size_t ws_size,
                              hipStream_t stream) {
  const float* pred = (const float*)d_in[0];
  const float* logits = (const float*)d_in[1];

  char* ws = (char*)d_ws;
  size_t off = 0;
  auto alloc = [&](size_t bytes) -> void* {
    void* p = ws + off;
    off += (bytes + 255) & ~(size_t)255;
    return p;
  };
  uint32_t* sw    = (uint32_t*)alloc((size_t)BATCH * NDET * 4);
  uint8_t*  cls8  = (uint8_t*)alloc((size_t)BATCH * NDET);
  uint32_t* s_n   = (uint32_t*)alloc((size_t)BATCH * KTOP * 4);
  float*    s_sc  = (float*)alloc((size_t)BATCH * KTOP * 4);
  float*    s_cl  = (float*)alloc((size_t)BATCH * KTOP * 4);
  uint32_t* clsbm = (uint32_t*)alloc((size_t)BATCH * BMW * 4);
  float*    s_box = (float*)alloc((size_t)BATCH * KTOP * 16);
  float*    s_ob  = (float*)alloc((size_t)BATCH * KTOP * 16);
  uint32_t* keepb = (uint32_t*)alloc((size_t)BATCH * 64 * 4);
  (void)ws_size; (void)in_sizes; (void)n_in;

  k_keys<<<(BATCH * NDET) / 64, 256, 0, stream>>>(pred, sw, cls8);
  k_sel<<<BATCH, 1024, 0, stream>>>(sw, cls8, pred, s_n, s_sc, s_cl, clsbm, s_box, s_ob, keepb);
  k_cnms<<<BATCH * NCLS, 64, 0, stream>>>(clsbm, s_ob, keepb);
  k_outw<<<BATCH * BPB, 256, 0, stream>>>(keepb, s_n, s_sc, s_cl, s_box, logits, (fx4*)d_out);
}

// Round 16
// 100.476 us; speedup vs baseline: 1.8749x; 1.0849x over previous
//
#include <hip/hip_runtime.h>
#include <stdint.h>

#define BATCH 16
#define NDET 25200
#define NCLS 80
#define PREDC 85
#define KTOP 2048
#define MAXDET 300
#define OUTC 86
#define CONF_THR 0.4f
#define IOU_THR 0.45f
#define MAXWH 4096.0f
#define INVHI 0xBF800000u       // ~mono(-1.0f): score word of invalid rows
#define BMW (NCLS * 64)         // class bitmap words per batch (80 classes x 64)
#define NB 8192                 // flat histogram bins
#define QPB ((MAXDET * OUTC) / 4)   // 6450 float4 per batch
#define BPB ((QPB + 255) / 256)     // 26 blocks per batch

typedef float fx4 __attribute__((ext_vector_type(4)));

// ---- monotone float<->uint mapping (ascending) ----
__device__ __forceinline__ uint32_t mono_f32(float f) {
  uint32_t u = __float_as_uint(f);
  return (u & 0x80000000u) ? ~u : (u | 0x80000000u);
}
__device__ __forceinline__ float unmono_f32(uint32_t m) {
  uint32_t u = (m & 0x80000000u) ? (m & 0x7FFFFFFFu) : ~m;
  return __uint_as_float(u);
}

// K1: obj-gated score/argmax, quad (4 lanes) per row.
__global__ void __launch_bounds__(256) k_keys(const float* __restrict__ pred,
                                              uint32_t* __restrict__ sw,
                                              uint8_t* __restrict__ cls8) {
  int gq = blockIdx.x * 64 + (threadIdx.x >> 2);   // 64 rows per block
  int q = threadIdx.x & 3;
  const float* row = pred + (size_t)gq * PREDC;
  float obj = row[4];
  float score = -1.0f;
  uint32_t cl = 0;
  if (obj > CONF_THR) {
    float best = -1e30f;
    int bc = 0;
#pragma unroll
    for (int k = 0; k < 5; ++k) {
#pragma unroll
      for (int j = 0; j < 4; ++j) {
        int c = k * 16 + q * 4 + j;                 // ascending within lane
        float s = __fmul_rn(row[5 + c], obj);       // single-rounded, no contraction
        if (s > best) { best = s; bc = c; }         // strict > : first max
      }
    }
    for (int d = 1; d <= 2; d <<= 1) {              // quad reduce
      float vo = __shfl_xor(best, d);
      int co = __shfl_xor(bc, d);
      if (vo > best || (vo == best && co < bc)) { best = vo; bc = co; }
    }
    if (best > CONF_THR) { score = best; cl = (uint32_t)bc; }
  }
  if (q == 0) {
    sw[gq] = ~mono_f32(score);
    cls8[gq] = (uint8_t)cl;
  }
}

// K2: fused radix-select (2x13-bit) + exact tie refine + collect + hybrid
// register/LDS bitonic sort + derive (+ class bitmap). One block per batch.
__global__ void __launch_bounds__(1024) k_sel(
    const uint32_t* __restrict__ sw, const uint8_t* __restrict__ cls8,
    const float* __restrict__ pred,
    uint32_t* __restrict__ s_n, float* __restrict__ s_score, float* __restrict__ s_clsf,
    uint32_t* __restrict__ clsbm, float* __restrict__ s_box, float* __restrict__ s_obox,
    uint32_t* __restrict__ keepbm) {
  __shared__ uint64_t sk[KTOP];        // 16 KB
  __shared__ uint32_t hist[NB];        // 32 KB (reused as class bitmap later)
  __shared__ uint32_t seg[64];
  __shared__ uint32_t sh_digit, sh_cnt, sh_k;
  __shared__ uint32_t ncol;
  int b = blockIdx.x, tid = threadIdx.x, lane = tid & 63;
  const uint32_t* swb = sw + (size_t)b * NDET;
  const uint8_t* clb = cls8 + (size_t)b * NDET;
  const uint4* sw4 = (const uint4*)swb;
  if (tid == 0) { sh_k = KTOP; ncol = 0; }
  if (tid < 64) keepbm[b * 64 + tid] = 0;

#define CLEAR_HIST() { __syncthreads(); \
  for (int i = tid; i < NB; i += 1024) hist[i] = 0; \
  __syncthreads(); }

#define FIND() { __syncthreads(); \
  if (tid < 64) { uint32_t s_ = 0; \
    for (int i_ = 0; i_ < NB / 64; ++i_) s_ += hist[tid * (NB / 64) + i_]; \
    seg[tid] = s_; } \
  __syncthreads(); \
  if (tid == 0) { uint32_t k_ = sh_k, cum_ = 0; int S_ = 0; \
    for (; S_ < 63; ++S_) { if (cum_ + seg[S_] >= k_) break; cum_ += seg[S_]; } \
    int d_ = S_ * (NB / 64); \
    for (;; ++d_) { if (cum_ + hist[d_] >= k_) break; cum_ += hist[d_]; } \
    sh_digit = (uint32_t)d_; sh_cnt = hist[d_]; sh_k = k_ - cum_; } \
  __syncthreads(); }

  // ---- pass A: bits [25:13] of (hi - 0x40000000); invalid -> bin 8191 ----
  CLEAR_HIST();
  {
    uint32_t invc = 0;
#define PA(s) { if ((s) == INVHI) ++invc; \
    else atomicAdd(&hist[((s) - 0x40000000u) >> 13], 1u); }
    for (int i = tid; i < NDET / 4; i += 1024) {
      uint4 v = sw4[i];
      PA(v.x) PA(v.y) PA(v.z) PA(v.w)
    }
    if (invc) atomicAdd(&hist[NB - 1], invc);
  }
  FIND();
  uint32_t dA = sh_digit;
  uint32_t sstar, E, r, Lstar = 0xFFFFFFFFu;
  if (dA == NB - 1) {
    sstar = INVHI; E = sh_cnt; r = sh_k;
  } else {
    // ---- pass B: bits [12:0] among prefix dA ----
    CLEAR_HIST();
    for (int i = tid; i < NDET / 4; i += 1024) {
      uint4 v = sw4[i];
#define PB(s) { if ((s) != INVHI && (((s) - 0x40000000u) >> 13) == dA) \
      atomicAdd(&hist[(s) & 0x1FFFu], 1u); }
      PB(v.x) PB(v.y) PB(v.z) PB(v.w)
    }
    FIND();
    sstar = 0x40000000u + (dA << 13) + sh_digit;
    E = sh_cnt; r = sh_k;
  }

  if (r < E) {
    // exact tie refine: r-th smallest low=(n<<7)|cls (22 bits) among hi==sstar.
    CLEAR_HIST();
    for (int n = tid; n < NDET; n += 1024) {
      if (swb[n] == sstar) {
        uint32_t low = ((uint32_t)n << 7) | clb[n];
        atomicAdd(&hist[low >> 11], 1u);
      }
    }
    FIND();
    uint32_t dr0 = sh_digit;
    CLEAR_HIST();
    for (int n = tid; n < NDET; n += 1024) {
      if (swb[n] == sstar) {
        uint32_t low = ((uint32_t)n << 7) | clb[n];
        if ((low >> 11) == dr0) atomicAdd(&hist[low & 0x7FFu], 1u);
      }
    }
    FIND();
    Lstar = (dr0 << 11) | sh_digit;
  }

  // ---- collect exactly KTOP keys ----
  for (int n = tid; n < NDET; n += 1024) {
    uint32_t hi = swb[n];
    uint32_t low = 0;
    bool inc = false;
    if (hi < sstar) inc = true;
    else if (hi == sstar) { low = ((uint32_t)n << 7) | clb[n]; inc = (low <= Lstar); }
    uint64_t ball = __ballot(inc);
    uint32_t bse = 0;
    if (lane == 0) bse = atomicAdd(&ncol, (uint32_t)__popcll(ball));
    bse = __shfl(bse, 0);
    if (inc) {
      if (hi < sstar) low = ((uint32_t)n << 7) | clb[n];
      uint32_t pos = bse + (uint32_t)__popcll(ball & ((1ull << lane) - 1ull));
      if (pos < KTOP) sk[pos] = ((uint64_t)hi << 32) | low;
    }
  }
  __syncthreads();

  // ---- hybrid register/LDS bitonic sort (ascending; same network as the
  // all-LDS version, keys distinct). 16 waves x 128-elem chunks held in 2
  // regs/lane; j<128 phases are shfl/in-lane (56 of 66, barrier-free);
  // only j>=128 phases (10) round-trip LDS. Round-15: 66-barrier all-LDS
  // sort was ~50us of k_sel's 76.8 at 2.6% occupancy.
  {
    int wv = tid >> 6, ln = tid & 63;
    int i1 = wv * 128 + ln;
    int i2 = i1 + 64;
    uint64_t lo = sk[i1], hi = sk[i2];

#define CMPEX_SHFL(j, kk) { \
      uint64_t plo = __shfl_xor((unsigned long long)lo, (j)); \
      uint64_t phi = __shfl_xor((unsigned long long)hi, (j)); \
      bool low1 = ((ln & (j)) == 0); \
      bool km1 = (low1 == ((i1 & (kk)) == 0)); \
      lo = km1 ? (lo < plo ? lo : plo) : (lo > plo ? lo : plo); \
      bool km2 = (low1 == ((i2 & (kk)) == 0)); \
      hi = km2 ? (hi < phi ? hi : phi) : (hi > phi ? hi : phi); }
#define CMPEX_LANE(kk) { \
      bool asc_ = ((i1 & (kk)) == 0); \
      uint64_t mn = lo < hi ? lo : hi; \
      uint64_t mx = lo < hi ? hi : lo; \
      lo = asc_ ? mn : mx; hi = asc_ ? mx : mn; }

    for (int kk = 2; kk <= 128; kk <<= 1) {
      for (int j = kk >> 1; j > 0; j >>= 1) {
        if (j == 64) { CMPEX_LANE(kk) }
        else CMPEX_SHFL(j, kk)
      }
    }
    for (int kk = 256; kk <= KTOP; kk <<= 1) {
      for (int j = kk >> 1; j >= 128; j >>= 1) {
        sk[i1] = lo; sk[i2] = hi;
        __syncthreads();
        uint64_t p1 = sk[i1 ^ j], p2 = sk[i2 ^ j];
        bool km1 = (((i1 & j) == 0) == ((i1 & kk) == 0));
        lo = km1 ? (lo < p1 ? lo : p1) : (lo > p1 ? lo : p1);
        bool km2 = (((i2 & j) == 0) == ((i2 & kk) == 0));
        hi = km2 ? (hi < p2 ? hi : p2) : (hi > p2 ? hi : p2);
        __syncthreads();
      }
      for (int j = 64; j > 0; j >>= 1) {
        if (j == 64) { CMPEX_LANE(kk) }
        else CMPEX_SHFL(j, kk)
      }
    }
    sk[i1] = lo; sk[i2] = hi;
  }
  __syncthreads();

  // ---- class bitmap (reuse hist space; BMW=5120 <= NB) ----
  uint32_t* bm = hist;
  for (int i = tid; i < BMW; i += 1024) bm[i] = 0;
  __syncthreads();

  // ---- derive arrays ----
  for (int rr = tid; rr < KTOP; rr += 1024) {
    uint64_t key = sk[rr];
    float score = unmono_f32(~(uint32_t)(key >> 32));
    uint32_t low = (uint32_t)key;
    uint32_t n = low >> 7;
    uint32_t cls = low & 127u;
    if (score > 0.0f) atomicOr(&bm[cls * 64 + (rr >> 5)], 1u << (rr & 31));
    const float* p = pred + ((size_t)b * NDET + n) * PREDC;
    float x = p[0], y = p[1], w = p[2], h = p[3];
    float hw = __fmul_rn(w, 0.5f), hh = __fmul_rn(h, 0.5f);
    float x1 = __fsub_rn(x, hw), y1 = __fsub_rn(y, hh);
    float x2 = __fadd_rn(x, hw), y2 = __fadd_rn(y, hh);
    float clsf = (float)cls;
    float off = __fmul_rn(clsf, MAXWH);
    size_t o = (size_t)b * KTOP + rr;
    s_n[o] = n;
    s_score[o] = score;
    s_clsf[o] = clsf;
    s_box[o * 4 + 0] = x1; s_box[o * 4 + 1] = y1;
    s_box[o * 4 + 2] = x2; s_box[o * 4 + 3] = y2;
    s_obox[o * 4 + 0] = __fadd_rn(x1, off); s_obox[o * 4 + 1] = __fadd_rn(y1, off);
    s_obox[o * 4 + 2] = __fadd_rn(x2, off); s_obox[o * 4 + 3] = __fadd_rn(y2, off);
  }
  __syncthreads();
  for (int i = tid; i < BMW; i += 1024) clsbm[(size_t)b * BMW + i] = bm[i];
}

// K3: per-(batch,class) greedy NMS (exact decomposition: cross-class IoU == 0).
__global__ void __launch_bounds__(64) k_cnms(
    const uint32_t* __restrict__ clsbm, const float* __restrict__ s_obox,
    uint32_t* __restrict__ keepbm) {
  __shared__ uint16_t memb[KTOP];                 // 4 KB
  __shared__ float bx1[KTOP], by1[KTOP], bx2[KTOP], by2[KTOP];  // 32 KB
  __shared__ uint64_t aliveM[KTOP / 64];
  int b = blockIdx.x / NCLS, c = blockIdx.x % NCLS;
  int lane = threadIdx.x;
  uint32_t w = clsbm[(size_t)b * BMW + c * 64 + lane];
  int cnt = __popc(w);
  int scan = cnt;
  for (int d = 1; d < 64; d <<= 1) {
    int v = __shfl_up(scan, d);
    if (lane >= d) scan += v;
  }
  int m = __shfl(scan, 63);
  if (m == 0) return;
  int p = scan - cnt;
  uint32_t ww = w;
  while (ww) { int t = __ffs(ww) - 1; ww &= ww - 1; memb[p++] = (uint16_t)(lane * 32 + t); }
  __syncthreads();
  for (int i = lane; i < m; i += 64) {
    const float* bp = s_obox + ((size_t)b * KTOP + memb[i]) * 4;
    bx1[i] = bp[0]; by1[i] = bp[1]; bx2[i] = bp[2]; by2[i] = bp[3];
  }
  __syncthreads();
  int nch = (m + 63) >> 6;
  for (int ch = 0; ch < nch; ++ch) {
    int base = ch * 64;
    int my = base + lane;
    bool has = my < m;
    float ax1 = 0, ay1 = 0, ax2 = 0, ay2 = 0, aarea = 0;
    if (has) {
      ax1 = bx1[my]; ay1 = by1[my]; ax2 = bx2[my]; ay2 = by2[my];
      aarea = __fmul_rn(__fsub_rn(ax2, ax1), __fsub_rn(ay2, ay1));
    }
    bool supp = false;
#define IOU_SUPP(j, guard) { \
      float jx1 = bx1[j], jy1 = by1[j], jx2 = bx2[j], jy2 = by2[j]; \
      float jarea = __fmul_rn(__fsub_rn(jx2, jx1), __fsub_rn(jy2, jy1)); \
      float ltx = fmaxf(jx1, ax1), lty = fmaxf(jy1, ay1); \
      float rbx = fminf(jx2, ax2), rby = fminf(jy2, ay2); \
      float wx = fmaxf(__fsub_rn(rbx, ltx), 0.0f); \
      float wy = fmaxf(__fsub_rn(rby, lty), 0.0f); \
      float inter = __fmul_rn(wx, wy); \
      float denom = __fadd_rn(__fsub_rn(__fadd_rn(jarea, aarea), inter), 1e-7f); \
      float iou = __fdiv_rn(inter, denom); \
      supp = supp || ((guard) && iou > IOU_THR); }
    for (int pc = 0; pc < ch; ++pc) {
      uint64_t aw = aliveM[pc];
      while (aw) {
        int e = __ffsll((unsigned long long)aw) - 1; aw &= aw - 1;
        int j = pc * 64 + e;
        IOU_SUPP(j, has)
      }
    }
    uint64_t sm = __ballot(supp);
    int csz = (m - base >= 64) ? 64 : (m - base);
    for (int d = 0; d < csz; ++d) {
      if (!((sm >> d) & 1ull)) {
        int j = base + d;
        IOU_SUPP(j, (lane > d) && has)
        sm = __ballot(supp);
      }
    }
    uint64_t vmask = (csz == 64) ? ~0ull : ((1ull << csz) - 1ull);
    if (lane == 0) aliveM[ch] = (~sm) & vmask;
    __syncthreads();
    if (has && !supp) {
      int rk = memb[my];
      atomicOr(&keepbm[b * 64 + (rk >> 5)], 1u << (rk & 31));
    }
  }
}

// K4: gather + DIRECT write to d_out. Per-batch blocks; slot->rank table
// rebuilt in LDS from keepbm. 16B nontemporal stores, max outstanding writes.
__global__ void __launch_bounds__(256) k_outw(
    const uint32_t* __restrict__ keepbm, const uint32_t* __restrict__ s_n,
    const float* __restrict__ s_score, const float* __restrict__ s_clsf,
    const float* __restrict__ s_box, const float* __restrict__ logits,
    fx4* __restrict__ dout) {
  __shared__ int src[MAXDET];
  int b = blockIdx.x / BPB;
  int jb = blockIdx.x % BPB;
  int tid = threadIdx.x;
  for (int s = tid; s < MAXDET; s += 256) src[s] = -1;
  __syncthreads();
  if (tid < 64) {
    uint32_t keep = keepbm[b * 64 + tid];
    uint32_t cnt = __popc(keep);
    uint32_t scan = cnt;
    for (int d = 1; d < 64; d <<= 1) {
      uint32_t v = __shfl_up(scan, d);
      if (tid >= d) scan += v;
    }
    uint32_t pfx = scan - cnt;
    int lo = tid * 32;
    while (keep) {
      int t = __ffs(keep) - 1;
      keep &= keep - 1;
      if (pfx < MAXDET) src[pfx] = lo + t;
      ++pfx;
    }
  }
  __syncthreads();
  int i = jb * 256 + tid;          // quad index within batch
  if (i >= QPB) return;
  float v0, v1, v2, v3;
#define GETV(k, dst) { \
    int idx = i * 4 + k; \
    int slot = idx / OUTC; \
    int c = idx - slot * OUTC; \
    int r = src[slot]; \
    float x = 0.0f; \
    if (r >= 0) { \
      size_t o = (size_t)b * KTOP + r; \
      if (c < 4) x = s_box[o * 4 + c]; \
      else if (c == 4) x = s_score[o]; \
      else if (c == 5) x = s_clsf[o]; \
      else x = logits[((size_t)b * NDET + s_n[o]) * NCLS + (c - 6)]; \
    } \
    dst = x; }
  GETV(0, v0) GETV(1, v1) GETV(2, v2) GETV(3, v3)
  fx4 f4 = {v0, v1, v2, v3};
  __builtin_nontemporal_store(f4, &dout[(size_t)b * QPB + i]);
}

extern "C" void kernel_launch(void* const* d_in, const int* in_sizes, int n_in,
                              void* d_out, int out_size, void* d_ws, size_t ws_size,
                              hipStream_t stream) {
  const float* pred = (const float*)d_in[0];
  const float* logits = (const float*)d_in[1];

  char* ws = (char*)d_ws;
  size_t off = 0;
  auto alloc = [&](size_t bytes) -> void* {
    void* p = ws + off;
    off += (bytes + 255) & ~(size_t)255;
    return p;
  };
  uint32_t* sw    = (uint32_t*)alloc((size_t)BATCH * NDET * 4);
  uint8_t*  cls8  = (uint8_t*)alloc((size_t)BATCH * NDET);
  uint32_t* s_n   = (uint32_t*)alloc((size_t)BATCH * KTOP * 4);
  float*    s_sc  = (float*)alloc((size_t)BATCH * KTOP * 4);
  float*    s_cl  = (float*)alloc((size_t)BATCH * KTOP * 4);
  uint32_t* clsbm = (uint32_t*)alloc((size_t)BATCH * BMW * 4);
  float*    s_box = (float*)alloc((size_t)BATCH * KTOP * 16);
  float*    s_ob  = (float*)alloc((size_t)BATCH * KTOP * 16);
  uint32_t* keepb = (uint32_t*)alloc((size_t)BATCH * 64 * 4);
  (void)ws_size; (void)in_sizes; (void)n_in;

  k_keys<<<(BATCH * NDET) / 64, 256, 0, stream>>>(pred, sw, cls8);
  k_sel<<<BATCH, 1024, 0, stream>>>(sw, cls8, pred, s_n, s_sc, s_cl, clsbm, s_box, s_ob, keepb);
  k_cnms<<<BATCH * NCLS, 64, 0, stream>>>(clsbm, s_ob, keepb);
  k_outw<<<BATCH * BPB, 256, 0, stream>>>(keepb, s_n, s_sc, s_cl, s_box, logits, (fx4*)d_out);
}